// Round 12
// baseline (16317.091 us; speedup 1.0000x reference)
//
#include <hip/hip_runtime.h>
#include <hip/hip_cooperative_groups.h>
#include <stdint.h>
#include <stddef.h>

#define TT 512
#define BB 64
#define XX 64
#define HH 512
#define ZZ 128
#define RR 1024

typedef __attribute__((ext_vector_type(8))) short short8;
typedef __attribute__((ext_vector_type(4))) float f32x4;
typedef long long i64t;
static_assert(sizeof(short8) == 16, "short8 must be 16B");

// ---------------- ws layout (bytes) ----------------
#define OFF_WID   0UL
#define OFF_WHD   393216UL       // Wh_d bf16 (dead after k_gru_d)
#define OFF_WIA   6684672UL      // RIA: repacked Wi_a (6.53 MB)
#define OFF_WHA   13369344UL
#define OFF_WQ1   19660800UL     // RQ1D: repacked Wq1[:, :1024] (1 MB); fp8 q-weights overlay after k_pre1
#define OFF_WQ2   20840448UL     // (unused bf16 slot)
#define OFF_WQ3   21364736UL
#define OFF_WQG   21889024UL
#define OFF_WP1   22151168UL     // RP1 (1.15 MB)
#define OFF_WP2   23330816UL     // RP2
#define OFF_WP3   23855104UL     // RP3
#define OFF_WPG   24379392UL     // RPG
#define OFF_WD    24641536UL     // RD (144 KB)
#define OFF_XBF   24788992UL
#define OFF_D     28983296UL
#define OFF_A     96092160UL
#define OFF_PRE1  163201024UL    // XGC ping/pong (2x25.2MB) before k_pre1; BAR_D during gru_d
#define OFF_ZBF   196755456UL
#define OFF_QMU   205144064UL
#define OFF_QSD   221921280UL    // BAR_A during a-chunks
#define OFF_HA    238698496UL    // h ping-pong during a-chunks; PROG counters during fused qscan+pnet
#define OFF_ACC   238960640UL
#define WS_NEED   238961152UL
#define XGC_HALF  25165824UL     // 64*64*3072*2 bytes per chunk buffer

__device__ __forceinline__ f32x4 mfma16(short8 a, short8 b, f32x4 c) {
  return __builtin_amdgcn_mfma_f32_16x16x32_bf16(a, b, c, 0, 0, 0);
}
__device__ __forceinline__ f32x4 mfma8(i64t a, i64t b, f32x4 c) {
  return __builtin_amdgcn_mfma_f32_16x16x32_fp8_fp8(a, b, c, 0, 0, 0);
}
__device__ __forceinline__ float bf2f(short s) {
  union { unsigned int u; float f; } v;
  v.u = ((unsigned int)(unsigned short)s) << 16;
  return v.f;
}
__device__ __forceinline__ short f2bf(float f) {
  union { float f; unsigned int u; } v; v.f = f;
  unsigned int u = v.u;
  unsigned int r = (u + 0x7fffu + ((u >> 16) & 1u)) >> 16;
  return (short)(unsigned short)r;
}
__device__ __forceinline__ float sigm(float x) { return 1.f / (1.f + __expf(-x)); }
__device__ __forceinline__ float tanh_(float x) { return 1.f - 2.f / (__expf(2.f * x) + 1.f); }
__device__ __forceinline__ float lrelu(float x) { return x > 0.f ? x : 0.01f * x; }
__device__ __forceinline__ float splus(float x) { return x > 15.f ? x : __logf(1.f + __expf(x)); }
__device__ __forceinline__ f32x4 fzero() { f32x4 v; v[0]=0.f; v[1]=0.f; v[2]=0.f; v[3]=0.f; return v; }
__device__ __forceinline__ int sw(int row, int col) {
  return row * 512 + ((((col >> 3) ^ (row & 7)) << 3) | (col & 7));
}

// pack 4 adjacent lanes' fp8 bytes -> one dword LDS store by lane with (n&3)==0.
__device__ __forceinline__ void st4_fp8(unsigned char* p, float v, int n) {
  int b = __builtin_amdgcn_cvt_pk_fp8_f32(v, v, 0, false) & 0xff;
  int pr = b | (__shfl_xor(b, 1) << 8);
  int qd = pr | (__shfl_xor(pr, 2) << 16);
  if ((n & 3) == 0) *(int*)p = qd;
}

// lightweight device barrier: monotone counter, NO L2 writeback.
__device__ __forceinline__ void fastbar(int* cnt, int target) {
  __syncthreads();
  if (threadIdx.x == 0) {
    __hip_atomic_fetch_add(cnt, 1, __ATOMIC_RELAXED, __HIP_MEMORY_SCOPE_AGENT);
    while (__hip_atomic_load(cnt, __ATOMIC_RELAXED, __HIP_MEMORY_SCOPE_AGENT) < target) {
      __builtin_amdgcn_s_sleep(2);
    }
  }
  __syncthreads();
  __builtin_amdgcn_fence(__ATOMIC_ACQUIRE, "agent");
}

__device__ __forceinline__ void store_pair_agent(short* base, float hv, int n) {
  unsigned int lo = (unsigned int)(unsigned short)f2bf(hv);
  unsigned int other = __shfl_xor(lo, 1);
  if (!(n & 1)) {
    unsigned int pack = lo | (other << 16);
    __hip_atomic_store((unsigned int*)base, pack, __ATOMIC_RELAXED, __HIP_MEMORY_SCOPE_AGENT);
  }
}

// write-through f32 store (device-scope visible after vmcnt drain)
__device__ __forceinline__ void store_f32_agent(float* p, float v) {
  union { float f; unsigned int u; } c; c.f = v;
  __hip_atomic_store((unsigned int*)p, c.u, __ATOMIC_RELAXED, __HIP_MEMORY_SCOPE_AGENT);
}

__global__ __launch_bounds__(64)
void k_diag(float* out, float v) { if (threadIdx.x < 64) out[threadIdx.x] = v; }

__global__ __launch_bounds__(256)
void k_cast(const float* __restrict__ src, short* __restrict__ dst, int n) {
  int i = blockIdx.x * 256 + threadIdx.x;
  if (i < n) dst[i] = f2bf(src[i]);
}

// ===== repack fp32 W[N][ldK] window -> lane-major MFMA B-frag records (bf16) =====
__global__ __launch_bounds__(64)
void k_repack(const float* __restrict__ src, short* __restrict__ dst,
              int ldK, int koff, int nKC) {
  int bid = blockIdx.x;
  int cb = bid / nKC, kc = bid % nKC;
  int lane = threadIdx.x;
  int n = lane & 15, q = lane >> 4;
  const float* s = src + (size_t)(cb * 16 + n) * ldK + koff + kc * 32 + q * 8;
  short8 v;
  #pragma unroll
  for (int j = 0; j < 8; ++j) v[j] = f2bf(s[j]);
  *(short8*)(dst + ((size_t)(cb * nKC + kc) * 64 + lane) * 8) = v;
}

// ===== repack fp32 -> fp8 e4m3 records (weights scaled x16) =====
__global__ __launch_bounds__(64)
void k_repack8(const float* __restrict__ src, unsigned char* __restrict__ dst,
               int ldK, int koff, int nKC) {
  int bid = blockIdx.x;
  int cb = bid / nKC, kc = bid % nKC;
  int lane = threadIdx.x;
  int n = lane & 15, q = lane >> 4;
  const float* s = src + (size_t)(cb * 16 + n) * ldK + koff + kc * 32 + q * 8;
  int lo = 0, hi = 0;
  lo = __builtin_amdgcn_cvt_pk_fp8_f32(16.f * s[0], 16.f * s[1], lo, false);
  lo = __builtin_amdgcn_cvt_pk_fp8_f32(16.f * s[2], 16.f * s[3], lo, true);
  hi = __builtin_amdgcn_cvt_pk_fp8_f32(16.f * s[4], 16.f * s[5], hi, false);
  hi = __builtin_amdgcn_cvt_pk_fp8_f32(16.f * s[6], 16.f * s[7], hi, true);
  int* d = (int*)(dst + ((size_t)(cb * nKC + kc) * 64 + lane) * 8);
  d[0] = lo; d[1] = hi;
}

// ================= K1: forward deterministic GRU (d) =================
__global__ __launch_bounds__(256)
void k_gru_d(const short* __restrict__ xbf, const short* __restrict__ whd,
             const short* __restrict__ wid, const float* __restrict__ bi,
             const float* __restrict__ bh, short* __restrict__ dbuf, int* bar) {
  extern __shared__ short smem[];
  short* whs = smem;                 // [48][1032]
  short* wis = smem + 48 * 1032;     // [48][72]
  const int tid = threadIdx.x;
  const int lane = tid & 63;
  const int w = tid >> 6;
  const int q = lane >> 4, n = lane & 15;
  const int jb = (int)blockIdx.x * 16;

  for (int it = tid; it < 48 * 128; it += 256) {
    int g = it >> 7, kc = (it & 127) * 8;
    int grow = (g < 16) ? (jb + g) : (g < 32) ? (1024 + jb + g - 16) : (2048 + jb + g - 32);
    *(short8*)(&whs[g * 1032 + kc]) = *(const short8*)(whd + (size_t)grow * 1024 + kc);
  }
  for (int it = tid; it < 48 * 8; it += 256) {
    int g = it >> 3, kc = (it & 7) * 8;
    int grow = (g < 16) ? (jb + g) : (g < 32) ? (1024 + jb + g - 16) : (2048 + jb + g - 32);
    *(short8*)(&wis[g * 72 + kc]) = *(const short8*)(wid + (size_t)grow * 64 + kc);
  }
  __syncthreads();

  const int j = jb + n;
  const float bir = bi[j] + bh[j];
  const float biz = bi[1024 + j] + bh[1024 + j];
  const float bin = bi[2048 + j];
  const float bhn = bh[2048 + j];
  const int r = 16 * w + n;

  #pragma unroll 1
  for (int t = 1; t < TT; ++t) {
    const short* hbase = dbuf + (size_t)(t - 1) * BB * RR;
    const short* pa = hbase + (size_t)r * RR + q * 8;
    short8 Areg[32];
    #pragma unroll
    for (int i = 0; i < 32; ++i) Areg[i] = *(const short8*)(pa + 32 * i);
    short8 Xreg[2];
    if (t >= 2) {
      const short* px = xbf + ((size_t)r * TT + (t - 2)) * XX + q * 8;
      Xreg[0] = *(const short8*)(px);
      Xreg[1] = *(const short8*)(px + 32);
    }
    float hp[4];
    #pragma unroll
    for (int reg = 0; reg < 4; ++reg)
      hp[reg] = bf2f(hbase[(size_t)(16 * w + q * 4 + reg) * RR + j]);

    f32x4 ar = fzero(), az = fzero(), anh = fzero(), anu = fzero();
    #pragma unroll
    for (int i = 0; i < 32; ++i) {
      int kb = 32 * i;
      short8 Br = *(const short8*)(&whs[n * 1032 + kb + q * 8]);
      short8 Bz = *(const short8*)(&whs[(16 + n) * 1032 + kb + q * 8]);
      short8 Bn = *(const short8*)(&whs[(32 + n) * 1032 + kb + q * 8]);
      ar = mfma16(Areg[i], Br, ar); az = mfma16(Areg[i], Bz, az); anh = mfma16(Areg[i], Bn, anh);
    }
    if (t >= 2) {
      #pragma unroll
      for (int i = 0; i < 2; ++i) {
        int kb = 32 * i;
        short8 Br = *(const short8*)(&wis[n * 72 + kb + q * 8]);
        short8 Bz = *(const short8*)(&wis[(16 + n) * 72 + kb + q * 8]);
        short8 Bn = *(const short8*)(&wis[(32 + n) * 72 + kb + q * 8]);
        ar = mfma16(Xreg[i], Br, ar); az = mfma16(Xreg[i], Bz, az); anu = mfma16(Xreg[i], Bn, anu);
      }
    }
    #pragma unroll
    for (int reg = 0; reg < 4; ++reg) {
      int m = 16 * w + q * 4 + reg;
      float rg = sigm(ar[reg] + bir);
      float zg = sigm(az[reg] + biz);
      float nn = tanh_(anu[reg] + bin + rg * (anh[reg] + bhn));
      float hv = (1.f - zg) * nn + zg * hp[reg];
      store_pair_agent(&dbuf[(size_t)t * BB * RR + (size_t)m * RR + (j & ~1)], hv, n);
    }
    if (t < TT - 1) fastbar(bar, 64 * t);
  }
}

// ======== K2b: precompute a-GRU input gates (chunk 0 only, 64 steps) =======
__global__ __launch_bounds__(256)
void k_prea(const short* __restrict__ xbf, const short* __restrict__ dbuf,
            const short* __restrict__ ria, const float* __restrict__ bi,
            const int* __restrict__ xsl, short* __restrict__ xgc, int t2base) {
  const int tl = blockIdx.x / 12, ct = blockIdx.x % 12;
  const int t2 = t2base + tl;
  const int tid = threadIdx.x, lane = tid & 63, w = tid >> 6;
  const int q = lane >> 4, n = lane & 15;
  const int cb = ct * 256 + w * 64;
  const int cbr0 = ct * 16 + w * 4;
  const short* pax[4]; const short* pad[4];
  #pragma unroll
  for (int mt = 0; mt < 4; ++mt) {
    int rowb = 16 * mt + n;
    int sl = xsl[rowb];
    int ti = (t2 < sl) ? (sl - 1 - t2) : t2;
    pax[mt] = xbf + ((size_t)rowb * TT + ti) * XX + q * 8;
    pad[mt] = dbuf + ((size_t)ti * BB + rowb) * RR + q * 8;
  }
  f32x4 acc[4][4];
  #pragma unroll
  for (int a = 0; a < 4; ++a)
    #pragma unroll
    for (int b = 0; b < 4; ++b) acc[a][b] = fzero();
  #pragma unroll
  for (int kc = 0; kc < 2; ++kc) {
    short8 Av[4], Bv[4];
    #pragma unroll
    for (int mt = 0; mt < 4; ++mt) Av[mt] = *(const short8*)(pax[mt] + kc * 32);
    #pragma unroll
    for (int nt = 0; nt < 4; ++nt)
      Bv[nt] = *(const short8*)(ria + ((size_t)((cbr0 + nt) * 34 + kc)) * 512 + lane * 8);
    #pragma unroll
    for (int mt = 0; mt < 4; ++mt)
      #pragma unroll
      for (int nt = 0; nt < 4; ++nt) acc[mt][nt] = mfma16(Av[mt], Bv[nt], acc[mt][nt]);
  }
  #pragma unroll 2
  for (int kc = 0; kc < 32; ++kc) {
    short8 Av[4], Bv[4];
    #pragma unroll
    for (int mt = 0; mt < 4; ++mt) Av[mt] = *(const short8*)(pad[mt] + kc * 32);
    #pragma unroll
    for (int nt = 0; nt < 4; ++nt)
      Bv[nt] = *(const short8*)(ria + ((size_t)((cbr0 + nt) * 34 + 2 + kc)) * 512 + lane * 8);
    #pragma unroll
    for (int mt = 0; mt < 4; ++mt)
      #pragma unroll
      for (int nt = 0; nt < 4; ++nt) acc[mt][nt] = mfma16(Av[mt], Bv[nt], acc[mt][nt]);
  }
  #pragma unroll
  for (int mt = 0; mt < 4; ++mt)
    #pragma unroll
    for (int nt = 0; nt < 4; ++nt) {
      int col = cb + 16 * nt + n;
      float bv = bi[col];
      #pragma unroll
      for (int reg = 0; reg < 4; ++reg) {
        int m = 16 * mt + q * 4 + reg;
        xgc[((size_t)tl * BB + m) * 3072 + col] = f2bf(acc[mt][nt][reg] + bv);
      }
    }
}

// ============ K3: a-GRU scan (64-step chunk) + fused prea workers ============
__global__ __launch_bounds__(256)
void k_gru_a2(const short* __restrict__ wha, const float* __restrict__ bh,
              const int* __restrict__ xsl, short* __restrict__ abuf,
              short* __restrict__ ha, const short* __restrict__ xgcA,
              short* __restrict__ xgcB, const short* __restrict__ xbf,
              const short* __restrict__ dbuf, const short* __restrict__ ria,
              const float* __restrict__ bia,
              int t2base, int nextbase, int* bar) {
  extern __shared__ short smem[];
  short* whs = smem;                 // [48][1032] (scan role only)
  const int tid = threadIdx.x;
  const int lane = tid & 63;
  const int w = tid >> 6;
  const int q = lane >> 4, n = lane & 15;
  const int bid = (int)blockIdx.x;

  if (bid >= 64) {
    // ---------------- worker role: prea for next chunk ----------------
    if (nextbase >= TT) return;
    const int wb = bid - 64;           // 0..191
    #pragma unroll 1
    for (int u = 0; u < 4; ++u) {
      const int unit = wb * 4 + u;     // 0..767
      const int tl = unit / 12, ct = unit % 12;
      const int t2 = nextbase + tl;
      const int cb = ct * 256 + w * 64;
      const int cbr0 = ct * 16 + w * 4;
      const short* pax[4]; const short* pad[4];
      #pragma unroll
      for (int mt = 0; mt < 4; ++mt) {
        int rowb = 16 * mt + n;
        int sl = xsl[rowb];
        int ti = (t2 < sl) ? (sl - 1 - t2) : t2;
        pax[mt] = xbf + ((size_t)rowb * TT + ti) * XX + q * 8;
        pad[mt] = dbuf + ((size_t)ti * BB + rowb) * RR + q * 8;
      }
      f32x4 acc[4][4];
      #pragma unroll
      for (int a = 0; a < 4; ++a)
        #pragma unroll
        for (int b = 0; b < 4; ++b) acc[a][b] = fzero();
      #pragma unroll
      for (int kc = 0; kc < 2; ++kc) {
        short8 Av[4], Bv[4];
        #pragma unroll
        for (int mt = 0; mt < 4; ++mt) Av[mt] = *(const short8*)(pax[mt] + kc * 32);
        #pragma unroll
        for (int nt = 0; nt < 4; ++nt)
          Bv[nt] = *(const short8*)(ria + ((size_t)((cbr0 + nt) * 34 + kc)) * 512 + lane * 8);
        #pragma unroll
        for (int mt = 0; mt < 4; ++mt)
          #pragma unroll
          for (int nt = 0; nt < 4; ++nt) acc[mt][nt] = mfma16(Av[mt], Bv[nt], acc[mt][nt]);
      }
      #pragma unroll 2
      for (int kc = 0; kc < 32; ++kc) {
        short8 Av[4], Bv[4];
        #pragma unroll
        for (int mt = 0; mt < 4; ++mt) Av[mt] = *(const short8*)(pad[mt] + kc * 32);
        #pragma unroll
        for (int nt = 0; nt < 4; ++nt)
          Bv[nt] = *(const short8*)(ria + ((size_t)((cbr0 + nt) * 34 + 2 + kc)) * 512 + lane * 8);
        #pragma unroll
        for (int mt = 0; mt < 4; ++mt)
          #pragma unroll
          for (int nt = 0; nt < 4; ++nt) acc[mt][nt] = mfma16(Av[mt], Bv[nt], acc[mt][nt]);
      }
      #pragma unroll
      for (int mt = 0; mt < 4; ++mt)
        #pragma unroll
        for (int nt = 0; nt < 4; ++nt) {
          int col = cb + 16 * nt + n;
          float bv = bia[col];
          #pragma unroll
          for (int reg = 0; reg < 4; ++reg) {
            int m = 16 * mt + q * 4 + reg;
            xgcB[((size_t)tl * BB + m) * 3072 + col] = f2bf(acc[mt][nt][reg] + bv);
          }
        }
    }
    return;
  }

  // ---------------- scan role (blocks 0..63) ----------------
  const int jb = bid * 16;
  for (int it = tid; it < 48 * 128; it += 256) {
    int g = it >> 7, kc = (it & 127) * 8;
    int grow = (g < 16) ? (jb + g) : (g < 32) ? (1024 + jb + g - 16) : (2048 + jb + g - 32);
    *(short8*)(&whs[g * 1032 + kc]) = *(const short8*)(wha + (size_t)grow * 1024 + kc);
  }
  __syncthreads();

  const int j = jb + n;
  const float bhr = bh[j];
  const float bhz = bh[1024 + j];
  const float bhn = bh[2048 + j];
  const int r = 16 * w + n;
  int sle[4];
  #pragma unroll
  for (int reg = 0; reg < 4; ++reg) sle[reg] = xsl[16 * w + q * 4 + reg];

  #pragma unroll 1
  for (int tl = 0; tl < 64; ++tl) {
    const int t2 = t2base + tl;
    int par = t2 & 1;
    const short* hbase = ha + (size_t)par * BB * RR;
    const short* pa = hbase + (size_t)r * RR + q * 8;
    short8 Areg[32];
    #pragma unroll
    for (int i = 0; i < 32; ++i) Areg[i] = *(const short8*)(pa + 32 * i);
    const short* xgs = xgcA + (size_t)tl * BB * 3072;
    float xr[4], xz[4], xn[4], hp[4];
    #pragma unroll
    for (int reg = 0; reg < 4; ++reg) {
      int m = 16 * w + q * 4 + reg;
      xr[reg] = bf2f(xgs[(size_t)m * 3072 + j]);
      xz[reg] = bf2f(xgs[(size_t)m * 3072 + 1024 + j]);
      xn[reg] = bf2f(xgs[(size_t)m * 3072 + 2048 + j]);
      hp[reg] = bf2f(hbase[(size_t)m * RR + j]);
    }
    f32x4 hr = fzero(), hz = fzero(), hn = fzero();
    #pragma unroll
    for (int i = 0; i < 32; ++i) {
      int kb = 32 * i;
      short8 Br = *(const short8*)(&whs[n * 1032 + kb + q * 8]);
      short8 Bz = *(const short8*)(&whs[(16 + n) * 1032 + kb + q * 8]);
      short8 Bn = *(const short8*)(&whs[(32 + n) * 1032 + kb + q * 8]);
      hr = mfma16(Areg[i], Br, hr); hz = mfma16(Areg[i], Bz, hz); hn = mfma16(Areg[i], Bn, hn);
    }
    #pragma unroll
    for (int reg = 0; reg < 4; ++reg) {
      int m = 16 * w + q * 4 + reg;
      int slm = sle[reg];
      int tie = (t2 < slm) ? (slm - 1 - t2) : t2;
      float rg = sigm(xr[reg] + hr[reg] + bhr);
      float ug = sigm(xz[reg] + hz[reg] + bhz);
      float nn = tanh_(xn[reg] + rg * (hn[reg] + bhn));
      float hv = (1.f - ug) * nn + ug * hp[reg];
      store_pair_agent(&ha[(size_t)(par ^ 1) * BB * RR + (size_t)m * RR + (j & ~1)], hv, n);
      store_pair_agent(&abuf[((size_t)tie * BB + m) * RR + (j & ~1)], hv, n);
    }
    if (tl < 63) fastbar(bar, 64 * (tl + 1));
  }
}

// ================= K4: pre1q = a @ Wq1[:, :1024]^T + bq1 ============
__global__ __launch_bounds__(256)
void k_pre1(const short* __restrict__ abuf, const short* __restrict__ rq1d,
            const float* __restrict__ bq1, short* __restrict__ pre1) {
  const int tid = threadIdx.x, lane = tid & 63, w = tid >> 6;
  const int q = lane >> 4, n = lane & 15;
  const int rt = blockIdx.x >> 1, ct = blockIdx.x & 1;
  const int cb = ct * 256 + w * 64;
  const int cbr0 = ct * 16 + w * 4;
  f32x4 acc[4][4];
  #pragma unroll
  for (int a = 0; a < 4; ++a)
    #pragma unroll
    for (int b = 0; b < 4; ++b) acc[a][b] = fzero();
  const short* pa = abuf + (size_t)(rt * 64) * RR;
  #pragma unroll 2
  for (int kc = 0; kc < 32; ++kc) {
    short8 Av[4], Bv[4];
    #pragma unroll
    for (int mt = 0; mt < 4; ++mt)
      Av[mt] = *(const short8*)(pa + (size_t)(16 * mt + n) * RR + kc * 32 + q * 8);
    #pragma unroll
    for (int nt = 0; nt < 4; ++nt)
      Bv[nt] = *(const short8*)(rq1d + ((size_t)((cbr0 + nt) * 32 + kc)) * 512 + lane * 8);
    #pragma unroll
    for (int mt = 0; mt < 4; ++mt)
      #pragma unroll
      for (int nt = 0; nt < 4; ++nt)
        acc[mt][nt] = mfma16(Av[mt], Bv[nt], acc[mt][nt]);
  }
  #pragma unroll
  for (int mt = 0; mt < 4; ++mt)
    #pragma unroll
    for (int nt = 0; nt < 4; ++nt) {
      int h = cb + 16 * nt + n;
      float bqv = bq1[h];
      #pragma unroll
      for (int reg = 0; reg < 4; ++reg) {
        int row = rt * 64 + 16 * mt + q * 4 + reg;
        pre1[(size_t)row * HH + h] = f2bf(acc[mt][nt][reg] + bqv);
      }
    }
}

// ====== K5: fused latent q scan (blocks 0-3) + pnet consumers (4-255) ======
// qscan publishes per-step progress via write-through payload (zbf/qmu/qsd as
// agent atomics; final __syncthreads drains vmcnt) + prog[qb] counter bump —
// the fastbar pattern. Worker blocks poll prog[0..3] >= t+1, acquire-fence,
// then run pnet for time t (512 active threads: tid>>8 = half; 2x64KB LDS).
// 252 otherwise-idle CUs absorb all of pnet under qscan's 5.4 ms.
__global__ __launch_bounds__(1024)
void k_qscan(const short* __restrict__ pre1,
             const unsigned char* __restrict__ rq1z8,
             const unsigned char* __restrict__ rq28,
             const unsigned char* __restrict__ rq38,
             const unsigned char* __restrict__ rqg8,
             const float* __restrict__ bq2,
             const float* __restrict__ bq3, const float* __restrict__ bqg,
             const float* __restrict__ eps,
             short* __restrict__ zbf, float* __restrict__ qmu, float* __restrict__ qsd,
             const short* __restrict__ dbuf,
             const short* __restrict__ rp1, const short* __restrict__ rp2,
             const short* __restrict__ rp3, const short* __restrict__ rpg,
             const short* __restrict__ rdd,
             const float* __restrict__ bp1, const float* __restrict__ bp2,
             const float* __restrict__ bp3, const float* __restrict__ bpg,
             const float* __restrict__ bdd,
             const float* __restrict__ x, const int* __restrict__ xsl,
             float* __restrict__ lp_acc, float* __restrict__ kl_acc,
             int* __restrict__ prog) {
  extern __shared__ unsigned char dsm8[];
  const int tid = threadIdx.x;
  const int bid = (int)blockIdx.x;

  if (bid < 4) {
    // ================== qscan role (qb = bid) ==================
    unsigned char* zs8 = dsm8;                   // [16][136] fp8 (z x8)
    unsigned char* hA8 = dsm8 + 2176;            // [16][520] fp8 (act x8)
    unsigned char* hB8 = dsm8 + 10496;           // [16][520] fp8
    float* gs = (float*)(dsm8 + 10496);          // [16][264] f32 overlays hB8
    const int lane = tid & 63, w = tid >> 6;     // w: 0..15
    const int q = lane >> 4, n = lane & 15;
    const int qb = bid;
    unsigned char* w2s = dsm8 + 27392 + w * 8192;
    const float INV128 = 0.0078125f;

    for (int i = tid; i < 2176; i += 1024) zs8[i] = 0;

    const unsigned char* r2a8 = rq28 + (size_t)(2 * w * 16) * 512 + lane * 8;
    const unsigned char* r3a8 = rq38 + (size_t)(2 * w * 16) * 512 + lane * 8;
    const unsigned char* rga8 = rqg8 + (size_t)(w * 16) * 512 + lane * 8;

    {
      const unsigned char* s0 = rq28 + (size_t)(2 * w * 16) * 512;
      #pragma unroll
      for (int s = 0; s < 8; ++s)
        *(i64t*)(w2s + s * 512 + lane * 8) = *(const i64t*)(s0 + (size_t)s * 512 + lane * 8);
      #pragma unroll
      for (int s = 0; s < 8; ++s)
        *(i64t*)(w2s + (8 + s) * 512 + lane * 8) = *(const i64t*)(s0 + (size_t)(16 + s) * 512 + lane * 8);
    }
    i64t B1[8];
    {
      const unsigned char* b1a = rq1z8 + (size_t)(2 * w * 4) * 512 + lane * 8;
      #pragma unroll
      for (int i = 0; i < 4; ++i) {
        B1[i * 2]     = *(const i64t*)(b1a + i * 512);
        B1[i * 2 + 1] = *(const i64t*)(b1a + 2048 + i * 512);
      }
    }
    i64t R3a[8], R3b[8];
    #pragma unroll
    for (int k2 = 0; k2 < 8; ++k2) {
      R3a[k2] = *(const i64t*)(r3a8 + k2 * 512);
      R3b[k2] = *(const i64t*)(r3a8 + 8192 + k2 * 512);
    }

    const size_t P1T = (size_t)BB * HH;
    const short* p1b = pre1 + (size_t)(qb * 16 + q * 4) * HH + w * 32 + n;
    short p1r[8];
    #pragma unroll
    for (int nt = 0; nt < 2; ++nt)
      #pragma unroll
      for (int rg2 = 0; rg2 < 4; ++rg2)
        p1r[nt * 4 + rg2] = p1b[(size_t)rg2 * HH + nt * 16];
    const float* ep0 = eps + (size_t)(qb * 16 + (tid >> 7)) * ZZ + (tid & 127);
    const float* ep1 = ep0 + (size_t)8 * ZZ;
    __syncthreads();

    #pragma unroll 1
    for (int t = 0; t < TT; ++t) {
      float e0 = ep0[(size_t)t * (BB * ZZ)];
      float e1 = ep1[(size_t)t * (BB * ZZ)];
      float p1v[2][4];
      #pragma unroll
      for (int nt = 0; nt < 2; ++nt)
        #pragma unroll
        for (int rg2 = 0; rg2 < 4; ++rg2)
          p1v[nt][rg2] = bf2f(p1r[nt * 4 + rg2]);
      short p1n[8];
      if (t + 1 < TT) {
        const short* pb = p1b + (size_t)(t + 1) * P1T;
        #pragma unroll
        for (int nt = 0; nt < 2; ++nt)
          #pragma unroll
          for (int rg2 = 0; rg2 < 4; ++rg2)
            p1n[nt * 4 + rg2] = pb[(size_t)rg2 * HH + nt * 16];
      }
      // ---- L1 ----
      {
        f32x4 a0 = fzero(), a1 = fzero();
        #pragma unroll
        for (int i = 0; i < 4; ++i) {
          i64t A = *(const i64t*)(zs8 + n * 136 + i * 32 + q * 8);
          a0 = mfma8(A, B1[i * 2], a0);
          a1 = mfma8(A, B1[i * 2 + 1], a1);
        }
        #pragma unroll
        for (int nt = 0; nt < 2; ++nt) {
          f32x4 av = nt ? a1 : a0;
          int colb = w * 32 + nt * 16;
          #pragma unroll
          for (int rg2 = 0; rg2 < 4; ++rg2) {
            float val = lrelu(av[rg2] * INV128 + p1v[nt][rg2]);
            st4_fp8(hA8 + (q * 4 + rg2) * 520 + colb + (n & ~3), 8.f * val, n);
          }
        }
      }
      __syncthreads();
      // ---- L2 ----
      {
        f32x4 a0 = fzero(), a1 = fzero();
        #pragma unroll 1
        for (int c = 0; c < 4; ++c) {
          i64t Br[8];
          if (c < 2) {
            #pragma unroll
            for (int i = 0; i < 4; ++i) {
              Br[i * 2]     = *(const i64t*)(w2s + (c * 4 + i) * 512 + lane * 8);
              Br[i * 2 + 1] = *(const i64t*)(w2s + (8 + c * 4 + i) * 512 + lane * 8);
            }
          } else {
            #pragma unroll
            for (int i = 0; i < 4; ++i) {
              Br[i * 2]     = *(const i64t*)(r2a8 + (c * 4 + i) * 512);
              Br[i * 2 + 1] = *(const i64t*)(r2a8 + 8192 + (c * 4 + i) * 512);
            }
          }
          #pragma unroll
          for (int i = 0; i < 4; ++i) {
            i64t A = *(const i64t*)(hA8 + n * 520 + c * 128 + i * 32 + q * 8);
            a0 = mfma8(A, Br[i * 2], a0);
            a1 = mfma8(A, Br[i * 2 + 1], a1);
          }
        }
        #pragma unroll
        for (int nt = 0; nt < 2; ++nt) {
          f32x4 av = nt ? a1 : a0;
          int h = w * 32 + nt * 16 + n;
          float bv = bq2[h];
          int colb = w * 32 + nt * 16;
          #pragma unroll
          for (int rg2 = 0; rg2 < 4; ++rg2) {
            float val = lrelu(av[rg2] * INV128 + bv);
            st4_fp8(hB8 + (q * 4 + rg2) * 520 + colb + (n & ~3), 8.f * val, n);
          }
        }
      }
      __syncthreads();
      // ---- L3 ----
      {
        f32x4 a0 = fzero(), a1 = fzero();
        #pragma unroll 1
        for (int c = 0; c < 4; ++c) {
          i64t Br[8];
          if (c < 2) {
            #pragma unroll
            for (int i = 0; i < 4; ++i) {
              Br[i * 2]     = R3a[c * 4 + i];
              Br[i * 2 + 1] = R3b[c * 4 + i];
            }
          } else {
            #pragma unroll
            for (int i = 0; i < 4; ++i) {
              Br[i * 2]     = *(const i64t*)(r3a8 + (c * 4 + i) * 512);
              Br[i * 2 + 1] = *(const i64t*)(r3a8 + 8192 + (c * 4 + i) * 512);
            }
          }
          #pragma unroll
          for (int i = 0; i < 4; ++i) {
            i64t A = *(const i64t*)(hB8 + n * 520 + c * 128 + i * 32 + q * 8);
            a0 = mfma8(A, Br[i * 2], a0);
            a1 = mfma8(A, Br[i * 2 + 1], a1);
          }
        }
        #pragma unroll
        for (int nt = 0; nt < 2; ++nt) {
          f32x4 av = nt ? a1 : a0;
          int h = w * 32 + nt * 16 + n;
          float bv = bq3[h];
          int colb = w * 32 + nt * 16;
          #pragma unroll
          for (int rg2 = 0; rg2 < 4; ++rg2) {
            float val = lrelu(av[rg2] * INV128 + bv);
            st4_fp8(hA8 + (q * 4 + rg2) * 520 + colb + (n & ~3), 8.f * val, n);
          }
        }
      }
      __syncthreads();
      // ---- Gauss head ----
      {
        f32x4 ga = fzero();
        #pragma unroll 1
        for (int c = 0; c < 4; ++c) {
          i64t Br[4];
          #pragma unroll
          for (int i = 0; i < 4; ++i) Br[i] = *(const i64t*)(rga8 + (c * 4 + i) * 512);
          #pragma unroll
          for (int i = 0; i < 4; ++i) {
            i64t A = *(const i64t*)(hA8 + n * 520 + c * 128 + i * 32 + q * 8);
            ga = mfma8(A, Br[i], ga);
          }
        }
        int gc = w * 16 + n;
        float bv = bqg[gc];
        #pragma unroll
        for (int rg2 = 0; rg2 < 4; ++rg2) {
          float o = ga[rg2] * INV128 + bv;
          gs[(q * 4 + rg2) * 264 + gc] = (gc < 128) ? o : splus(o);
        }
      }
      __syncthreads();
      // ---- z update: payload as write-through agent atomics ----
      {
        int m0 = tid >> 7, zi0 = tid & 127;
        size_t off0 = ((size_t)t * BB + qb * 16 + m0) * ZZ + zi0;
        size_t off1 = off0 + (size_t)8 * ZZ;
        float mu0 = gs[m0 * 264 + zi0], sd0 = gs[m0 * 264 + 128 + zi0];
        float mu1 = gs[(m0 + 8) * 264 + zi0], sd1 = gs[(m0 + 8) * 264 + 128 + zi0];
        float zv0 = mu0 + sd0 * e0;
        float zv1 = mu1 + sd1 * e1;
        st4_fp8(zs8 + m0 * 136 + (zi0 & ~3), 8.f * zv0, zi0 & 15);
        st4_fp8(zs8 + (m0 + 8) * 136 + (zi0 & ~3), 8.f * zv1, zi0 & 15);
        store_pair_agent(zbf + (off0 - (zi0 & 1)), zv0, zi0);
        store_pair_agent(zbf + (off1 - (zi0 & 1)), zv1, zi0);
        store_f32_agent(qmu + off0, mu0); store_f32_agent(qmu + off1, mu1);
        store_f32_agent(qsd + off0, sd0); store_f32_agent(qsd + off1, sd1);
      }
      __syncthreads();   // drains vmcnt: payload globally visible
      if (tid == 0)
        __hip_atomic_fetch_add(prog + qb, 1, __ATOMIC_RELAXED, __HIP_MEMORY_SCOPE_AGENT);
      if (t + 1 < TT) {
        #pragma unroll
        for (int k2 = 0; k2 < 8; ++k2) p1r[k2] = p1n[k2];
      }
    }
    return;
  }

  // ================== pnet worker role (blocks 4..255) ==================
  const bool act = (tid < 512);
  const int half = (tid >> 8) & 1;
  const int lt = tid & 255;
  const int lane = tid & 63;
  const int w4 = lt >> 6;
  const int q = lane >> 4, n = lane & 15;
  const int rg = w4 & 1, cgp = w4 >> 1;
  const int rl = 16 * rg + n;
  const int rA = 32 * half + rl;
  const int ml0 = 16 * rg + q * 4;
  const int b0 = 32 * half + ml0;
  short* bufA = (short*)(dsm8 + half * 65536);
  short* bufB = bufA + 16384;
  float* gs = (float*)bufB;

  #pragma unroll 1
  for (int t = bid - 4; t < TT; t += 252) {
    if (tid < 4) {
      while (__hip_atomic_load(prog + tid, __ATOMIC_RELAXED, __HIP_MEMORY_SCOPE_AGENT) < t + 1)
        __builtin_amdgcn_s_sleep(2);
    }
    __syncthreads();
    __builtin_amdgcn_fence(__ATOMIC_ACQUIRE, "agent");

    const short* dA = dbuf + ((size_t)t * BB + rA) * RR + q * 8;
    // ---- L1 ----
    if (act) {
      #pragma unroll 1
      for (int ch = 0; ch < 2; ++ch) {
        const int hbase = cgp * 256 + ch * 128;
        const int cbr0 = cgp * 16 + ch * 8;
        f32x4 acc[8];
        #pragma unroll
        for (int i = 0; i < 8; ++i) acc[i] = fzero();
        #pragma unroll 2
        for (int kc = 0; kc < 32; ++kc) {
          short8 A = *(const short8*)(dA + kc * 32);
          #pragma unroll
          for (int nt = 0; nt < 8; ++nt) {
            short8 Bv = *(const short8*)(rp1 + ((size_t)((cbr0 + nt) * 36 + kc)) * 512 + lane * 8);
            acc[nt] = mfma16(A, Bv, acc[nt]);
          }
        }
        if (t > 0) {
          const short* zAp = zbf + ((size_t)(t - 1) * BB + rA) * ZZ + q * 8;
          #pragma unroll
          for (int kc = 0; kc < 4; ++kc) {
            short8 A = *(const short8*)(zAp + kc * 32);
            #pragma unroll
            for (int nt = 0; nt < 8; ++nt) {
              short8 Bv = *(const short8*)(rp1 + ((size_t)((cbr0 + nt) * 36 + 32 + kc)) * 512 + lane * 8);
              acc[nt] = mfma16(A, Bv, acc[nt]);
            }
          }
        }
        #pragma unroll
        for (int nt = 0; nt < 8; ++nt) {
          int h = hbase + nt * 16 + n;
          float bv = bp1[h];
          #pragma unroll
          for (int reg = 0; reg < 4; ++reg)
            bufA[sw(ml0 + reg, h)] = f2bf(lrelu(acc[nt][reg] + bv));
        }
      }
    }
    __syncthreads();
    // ---- L2 ----
    if (act) {
      #pragma unroll 1
      for (int ch = 0; ch < 2; ++ch) {
        const int hbase = cgp * 256 + ch * 128;
        const int cbr0 = cgp * 16 + ch * 8;
        f32x4 acc[8];
        #pragma unroll
        for (int i = 0; i < 8; ++i) acc[i] = fzero();
        #pragma unroll 2
        for (int kc = 0; kc < 16; ++kc) {
          short8 A = *(const short8*)(&bufA[sw(rl, kc * 32 + q * 8)]);
          #pragma unroll
          for (int nt = 0; nt < 8; ++nt) {
            short8 Bv = *(const short8*)(rp2 + ((size_t)((cbr0 + nt) * 16 + kc)) * 512 + lane * 8);
            acc[nt] = mfma16(A, Bv, acc[nt]);
          }
        }
        #pragma unroll
        for (int nt = 0; nt < 8; ++nt) {
          int h = hbase + nt * 16 + n;
          float bv = bp2[h];
          #pragma unroll
          for (int reg = 0; reg < 4; ++reg)
            bufB[sw(ml0 + reg, h)] = f2bf(lrelu(acc[nt][reg] + bv));
        }
      }
    }
    __syncthreads();
    // ---- L3 ----
    if (act) {
      #pragma unroll 1
      for (int ch = 0; ch < 2; ++ch) {
        const int hbase = cgp * 256 + ch * 128;
        const int cbr0 = cgp * 16 + ch * 8;
        f32x4 acc[8];
        #pragma unroll
        for (int i = 0; i < 8; ++i) acc[i] = fzero();
        #pragma unroll 2
        for (int kc = 0; kc < 16; ++kc) {
          short8 A = *(const short8*)(&bufB[sw(rl, kc * 32 + q * 8)]);
          #pragma unroll
          for (int nt = 0; nt < 8; ++nt) {
            short8 Bv = *(const short8*)(rp3 + ((size_t)((cbr0 + nt) * 16 + kc)) * 512 + lane * 8);
            acc[nt] = mfma16(A, Bv, acc[nt]);
          }
        }
        #pragma unroll
        for (int nt = 0; nt < 8; ++nt) {
          int h = hbase + nt * 16 + n;
          float bv = bp3[h];
          #pragma unroll
          for (int reg = 0; reg < 4; ++reg)
            bufA[sw(ml0 + reg, h)] = f2bf(lrelu(acc[nt][reg] + bv));
        }
      }
    }
    __syncthreads();
    // ---- Gauss head ----
    f32x4 acc[8];
    if (act) {
      #pragma unroll
      for (int i = 0; i < 8; ++i) acc[i] = fzero();
      #pragma unroll 2
      for (int kc = 0; kc < 16; ++kc) {
        short8 A = *(const short8*)(&bufA[sw(rl, kc * 32 + q * 8)]);
        #pragma unroll
        for (int nt = 0; nt < 8; ++nt) {
          short8 Bv = *(const short8*)(rpg + ((size_t)((cgp * 8 + nt) * 16 + kc)) * 512 + lane * 8);
          acc[nt] = mfma16(A, Bv, acc[nt]);
        }
      }
      if (cgp == 0) {
        #pragma unroll
        for (int nt = 0; nt < 8; ++nt) {
          int zi = nt * 16 + n;
          float bv = bpg[zi];
          #pragma unroll
          for (int reg = 0; reg < 4; ++reg)
            gs[(ml0 + reg) * 128 + zi] = acc[nt][reg] + bv;
        }
      }
    }
    __syncthreads();
    if (act) {
      if (cgp == 1) {
        float kls[4] = {0.f, 0.f, 0.f, 0.f};
        #pragma unroll
        for (int nt = 0; nt < 8; ++nt) {
          int zi = nt * 16 + n;
          float bv = bpg[128 + zi];
          #pragma unroll
          for (int reg = 0; reg < 4; ++reg) {
            int b = b0 + reg;
            float ps = splus(acc[nt][reg] + bv);
            float pm = gs[(ml0 + reg) * 128 + zi];
            size_t off = ((size_t)t * BB + b) * ZZ + zi;
            float qm = qmu[off], qs = qsd[off];
            float dd = qm - pm;
            kls[reg] += __logf(ps / qs) + (qs * qs + dd * dd) / (2.f * ps * ps) - 0.5f;
          }
        }
        #pragma unroll
        for (int reg = 0; reg < 4; ++reg) {
          float v = kls[reg];
          v += __shfl_xor(v, 1); v += __shfl_xor(v, 2); v += __shfl_xor(v, 4); v += __shfl_xor(v, 8);
          if (n == 0) {
            int b = b0 + reg;
            if (t < xsl[b]) atomicAdd(kl_acc + b, v);
          }
        }
      }
      // ---- decoder ----
      f32x4 dacc[2];
      dacc[0] = fzero(); dacc[1] = fzero();
      {
        const short* zA = zbf + ((size_t)t * BB + rA) * ZZ + q * 8;
        #pragma unroll
        for (int kc = 0; kc < 4; ++kc) {
          short8 A = *(const short8*)(zA + kc * 32);
          #pragma unroll
          for (int nt = 0; nt < 2; ++nt) {
            short8 Bv = *(const short8*)(rdd + ((size_t)((cgp * 2 + nt) * 36 + kc)) * 512 + lane * 8);
            dacc[nt] = mfma16(A, Bv, dacc[nt]);
          }
        }
        #pragma unroll 2
        for (int kc = 0; kc < 32; ++kc) {
          short8 A = *(const short8*)(dA + kc * 32);
          #pragma unroll
          for (int nt = 0; nt < 2; ++nt) {
            short8 Bv = *(const short8*)(rdd + ((size_t)((cgp * 2 + nt) * 36 + 4 + kc)) * 512 + lane * 8);
            dacc[nt] = mfma16(A, Bv, dacc[nt]);
          }
        }
      }
      float lps[4] = {0.f, 0.f, 0.f, 0.f};
      #pragma unroll
      for (int nt = 0; nt < 2; ++nt) {
        int xi = cgp * 32 + nt * 16 + n;
        float bv = bdd[xi];
        #pragma unroll
        for (int reg = 0; reg < 4; ++reg) {
          int b = b0 + reg;
          float mu = dacc[nt][reg] + bv;
          float xv = x[((size_t)b * TT + t) * XX + xi];
          float e = xv - mu;
          lps[reg] += -0.5f * (e * e + 1.8378770664093453f);
        }
      }
      #pragma unroll
      for (int reg = 0; reg < 4; ++reg) {
        float v = lps[reg];
        v += __shfl_xor(v, 1); v += __shfl_xor(v, 2); v += __shfl_xor(v, 4); v += __shfl_xor(v, 8);
        if (n == 0) {
          int b = b0 + reg;
          if (t < xsl[b]) atomicAdd(lp_acc + b, v);
        }
      }
    }
    __syncthreads();
  }
}

__global__ __launch_bounds__(64)
void k_final(const float* __restrict__ lp, const float* __restrict__ kl, float* __restrict__ out) {
  int b = threadIdx.x;
  if (b < BB) out[b] = lp[b] - kl[b];
}

extern "C" void kernel_launch(void* const* d_in, const int* in_sizes, int n_in,
                              void* d_out, int out_size, void* d_ws, size_t ws_size,
                              hipStream_t stream) {
  if (ws_size < WS_NEED) {
    k_diag<<<1, 64, 0, stream>>>((float*)d_out, (float)ws_size);
    return;
  }
  const float* x    = (const float*)d_in[0];
  const float* eps  = (const float*)d_in[1];
  const float* Wi_d = (const float*)d_in[2];
  const float* Wh_d = (const float*)d_in[3];
  const float* bi_d = (const float*)d_in[4];
  const float* bh_d = (const float*)d_in[5];
  const float* Wi_a = (const float*)d_in[6];
  const float* Wh_a = (const float*)d_in[7];
  const float* bi_a = (const float*)d_in[8];
  const float* bh_a = (const float*)d_in[9];
  const float* Wq1 = (const float*)d_in[10]; const float* bq1 = (const float*)d_in[11];
  const float* Wq2 = (const float*)d_in[12]; const float* bq2 = (const float*)d_in[13];
  const float* Wq3 = (const float*)d_in[14]; const float* bq3 = (const float*)d_in[15];
  const float* Wqg = (const float*)d_in[16]; const float* bqg = (const float*)d_in[17];
  const float* Wp1 = (const float*)d_in[18]; const float* bp1 = (const float*)d_in[19];
  const float* Wp2 = (const float*)d_in[20]; const float* bp2 = (const float*)d_in[21];
  const float* Wp3 = (const float*)d_in[22]; const float* bp3 = (const float*)d_in[23];
  const float* Wpg = (const float*)d_in[24]; const float* bpg = (const float*)d_in[25];
  const float* Wd  = (const float*)d_in[26]; const float* bd  = (const float*)d_in[27];
  const int*   xsl = (const int*)d_in[28];

  char* ws = (char*)d_ws;
  short* WID  = (short*)(ws + OFF_WID);
  short* WHD  = (short*)(ws + OFF_WHD);
  short* RIA  = (short*)(ws + OFF_WIA);
  short* WHA  = (short*)(ws + OFF_WHA);
  short* RQ1D = (short*)(ws + OFF_WQ1);
  // fp8 q-net weights overlay the RQ1D region once k_pre1 has consumed it
  unsigned char* RQ28  = (unsigned char*)(ws + OFF_WQ1);            // 262144 B
  unsigned char* RQ38  = (unsigned char*)(ws + OFF_WQ1 + 262144UL); // 262144 B
  unsigned char* RQG8  = (unsigned char*)(ws + OFF_WQ1 + 524288UL); // 131072 B
  unsigned char* RQ1Z8 = (unsigned char*)(ws + OFF_WQ1 + 655360UL); // 65536 B
  short* RP1  = (short*)(ws + OFF_WP1);
  short* RP2  = (short*)(ws + OFF_WP2);
  short* RP3  = (short*)(ws + OFF_WP3);
  short* RPG  = (short*)(ws + OFF_WPG);
  short* RD   = (short*)(ws + OFF_WD);
  short* XBF  = (short*)(ws + OFF_XBF);
  short* DBUF = (short*)(ws + OFF_D);
  short* ABUF = (short*)(ws + OFF_A);
  short* PRE1 = (short*)(ws + OFF_PRE1);
  short* XGC0 = (short*)(ws + OFF_PRE1);
  short* XGC1 = (short*)(ws + OFF_PRE1 + XGC_HALF);
  short* ZBF  = (short*)(ws + OFF_ZBF);
  float* QMU  = (float*)(ws + OFF_QMU);
  float* QSD  = (float*)(ws + OFF_QSD);
  short* HA   = (short*)(ws + OFF_HA);
  float* LP   = (float*)(ws + OFF_ACC);
  float* KL   = (float*)(ws + OFF_ACC + 256);
  int*   BAR_D = (int*)(ws + OFF_PRE1);    // free during gru_d
  int*   BAR_A = (int*)(ws + OFF_QSD);     // free during a-chunks
  int*   PROG  = (int*)(ws + OFF_HA);      // HA dead after a-chunks

  hipMemsetAsync(ws + OFF_ACC, 0, 512, stream);
  hipMemsetAsync(ws + OFF_HA, 0, 262144, stream);
  hipMemsetAsync(ws + OFF_D, 0, 131072, stream);
  hipMemsetAsync(ws + OFF_PRE1, 0, 64, stream);    // BAR_D

  auto cast = [&](const float* s, short* d, int nel) {
    k_cast<<<(nel + 255) / 256, 256, 0, stream>>>(s, d, nel);
  };
  cast(Wi_d, WID, 3072 * 64);
  cast(Wh_d, WHD, 3072 * 1024);
  cast(Wh_a, WHA, 3072 * 1024);
  cast(x,   XBF,  64 * 512 * 64);

  // lane-major repacks (targets disjoint from their fp32 sources)
  k_repack<<<192 * 34, 64, 0, stream>>>(Wi_a, RIA, 1088, 0, 34);
  k_repack<<<32 * 32, 64, 0, stream>>>(Wq1, RQ1D, 1152, 0, 32);
  k_repack<<<32 * 36, 64, 0, stream>>>(Wp1, RP1, 1152, 0, 36);
  k_repack<<<32 * 16, 64, 0, stream>>>(Wp2, RP2, 512, 0, 16);
  k_repack<<<32 * 16, 64, 0, stream>>>(Wp3, RP3, 512, 0, 16);
  k_repack<<<16 * 16, 64, 0, stream>>>(Wpg, RPG, 512, 0, 16);
  k_repack<<<4 * 36, 64, 0, stream>>>(Wd, RD, 1152, 0, 36);

  hipFuncSetAttribute((const void*)k_gru_d, hipFuncAttributeMaxDynamicSharedMemorySize, 160 * 1024);
  hipFuncSetAttribute((const void*)k_gru_a2, hipFuncAttributeMaxDynamicSharedMemorySize, 160 * 1024);
  hipFuncSetAttribute((const void*)k_qscan, hipFuncAttributeMaxDynamicSharedMemorySize, 160 * 1024);

  {
    void* args[] = { (void*)&XBF, (void*)&WHD, (void*)&WID, (void*)&bi_d,
                     (void*)&bh_d, (void*)&DBUF, (void*)&BAR_D };
    hipLaunchCooperativeKernel((const void*)k_gru_d, dim3(64), dim3(256), args,
                               48 * 1032 * 2 + 48 * 72 * 2, stream);
  }

  // chunk 0 input gates (64 steps) into XGC0
  k_prea<<<64 * 12, 256, 0, stream>>>(XBF, DBUF, RIA, bi_a, xsl, XGC0, 0);

  // 8 fused launches: blocks 0-63 scan chunk c; blocks 64-255 prea chunk c+1
  for (int c = 0; c < 8; ++c) {
    hipMemsetAsync(ws + OFF_QSD, 0, 64, stream);   // reset BAR_A per chunk
    int base = c * 64;
    int nb = base + 64;
    short* xa = (c & 1) ? XGC1 : XGC0;
    short* xb = (c & 1) ? XGC0 : XGC1;
    void* args[] = { (void*)&WHA, (void*)&bh_a, (void*)&xsl, (void*)&ABUF,
                     (void*)&HA, (void*)&xa, (void*)&xb, (void*)&XBF,
                     (void*)&DBUF, (void*)&RIA, (void*)&bi_a,
                     (void*)&base, (void*)&nb, (void*)&BAR_A };
    hipLaunchCooperativeKernel((const void*)k_gru_a2, dim3(256), dim3(256), args,
                               48 * 1032 * 2, stream);
  }
  k_pre1<<<1024, 256, 0, stream>>>(ABUF, RQ1D, bq1, PRE1);
  // fp8 repacks overlay the (now-dead) RQ1D region — must follow k_pre1
  k_repack8<<<32 * 16, 64, 0, stream>>>(Wq2, RQ28, 512, 0, 16);
  k_repack8<<<32 * 16, 64, 0, stream>>>(Wq3, RQ38, 512, 0, 16);
  k_repack8<<<16 * 16, 64, 0, stream>>>(Wqg, RQG8, 512, 0, 16);
  k_repack8<<<32 * 4, 64, 0, stream>>>(Wq1, RQ1Z8, 1152, 1024, 4);
  // reset qscan->pnet progress counters (HA region dead now)
  hipMemsetAsync(ws + OFF_HA, 0, 64, stream);
  // fused qscan (blocks 0-3) + pnet consumers (blocks 4-255)
  // 158464 B dyn LDS: qscan layout; workers use first 2x64KB as bufA/bufB
  k_qscan<<<256, 1024, 158464, stream>>>(PRE1, RQ1Z8, RQ28, RQ38, RQG8,
                                         bq2, bq3, bqg, eps, ZBF, QMU, QSD,
                                         DBUF, RP1, RP2, RP3, RPG, RD,
                                         bp1, bp2, bp3, bpg, bd, x, xsl,
                                         LP, KL, PROG);
  k_final<<<1, 64, 0, stream>>>(LP, KL, (float*)d_out);
}

// Round 13
// 15948.755 us; speedup vs baseline: 1.0231x; 1.0231x over previous
//
#include <hip/hip_runtime.h>
#include <hip/hip_cooperative_groups.h>
#include <stdint.h>
#include <stddef.h>

#define TT 512
#define BB 64
#define XX 64
#define HH 512
#define ZZ 128
#define RR 1024

typedef __attribute__((ext_vector_type(8))) short short8;
typedef __attribute__((ext_vector_type(4))) float f32x4;
typedef long long i64t;
static_assert(sizeof(short8) == 16, "short8 must be 16B");

// ---------------- ws layout (bytes) ----------------
#define OFF_WID   0UL
#define OFF_WHD   393216UL       // Wh_d bf16 (dead after k_gru_d)
#define OFF_WIA   6684672UL      // RIA: repacked Wi_a (6.53 MB)
#define OFF_WHA   13369344UL
#define OFF_WQ1   19660800UL     // RQ1D: repacked Wq1[:, :1024] (1 MB); fp8 q-weights overlay after k_pre1
#define OFF_WQ2   20840448UL     // (unused bf16 slot)
#define OFF_WQ3   21364736UL
#define OFF_WQG   21889024UL
#define OFF_WP1   22151168UL     // RP1 (1.15 MB)
#define OFF_WP2   23330816UL     // RP2
#define OFF_WP3   23855104UL     // RP3
#define OFF_WPG   24379392UL     // RPG
#define OFF_WD    24641536UL     // RD (144 KB)
#define OFF_XBF   24788992UL
#define OFF_D     28983296UL
#define OFF_A     96092160UL
#define OFF_PRE1  163201024UL    // XGC ping/pong (2x25.2MB) before k_pre1; BAR_D during gru_d
#define OFF_ZBF   196755456UL
#define OFF_QMU   205144064UL
#define OFF_QSD   221921280UL    // BAR_A during a-chunks
#define OFF_HA    238698496UL
#define OFF_ACC   238960640UL
#define WS_NEED   238961152UL
#define XGC_HALF  25165824UL     // 64*64*3072*2 bytes per chunk buffer

__device__ __forceinline__ f32x4 mfma16(short8 a, short8 b, f32x4 c) {
  return __builtin_amdgcn_mfma_f32_16x16x32_bf16(a, b, c, 0, 0, 0);
}
__device__ __forceinline__ f32x4 mfma8(i64t a, i64t b, f32x4 c) {
  return __builtin_amdgcn_mfma_f32_16x16x32_fp8_fp8(a, b, c, 0, 0, 0);
}
__device__ __forceinline__ float bf2f(short s) {
  union { unsigned int u; float f; } v;
  v.u = ((unsigned int)(unsigned short)s) << 16;
  return v.f;
}
__device__ __forceinline__ short f2bf(float f) {
  union { float f; unsigned int u; } v; v.f = f;
  unsigned int u = v.u;
  unsigned int r = (u + 0x7fffu + ((u >> 16) & 1u)) >> 16;
  return (short)(unsigned short)r;
}
__device__ __forceinline__ float sigm(float x) { return 1.f / (1.f + __expf(-x)); }
__device__ __forceinline__ float tanh_(float x) { return 1.f - 2.f / (__expf(2.f * x) + 1.f); }
__device__ __forceinline__ float lrelu(float x) { return x > 0.f ? x : 0.01f * x; }
__device__ __forceinline__ float splus(float x) { return x > 15.f ? x : __logf(1.f + __expf(x)); }
__device__ __forceinline__ f32x4 fzero() { f32x4 v; v[0]=0.f; v[1]=0.f; v[2]=0.f; v[3]=0.f; return v; }
__device__ __forceinline__ int sw(int row, int col) {
  return row * 512 + ((((col >> 3) ^ (row & 7)) << 3) | (col & 7));
}

// pack 4 adjacent lanes' fp8 bytes -> one dword LDS store by lane with (n&3)==0.
__device__ __forceinline__ void st4_fp8(unsigned char* p, float v, int n) {
  int b = __builtin_amdgcn_cvt_pk_fp8_f32(v, v, 0, false) & 0xff;
  int pr = b | (__shfl_xor(b, 1) << 8);
  int qd = pr | (__shfl_xor(pr, 2) << 16);
  if ((n & 3) == 0) *(int*)p = qd;
}

// lightweight device barrier: monotone counter, NO L2 writeback.
__device__ __forceinline__ void fastbar(int* cnt, int target) {
  __syncthreads();
  if (threadIdx.x == 0) {
    __hip_atomic_fetch_add(cnt, 1, __ATOMIC_RELAXED, __HIP_MEMORY_SCOPE_AGENT);
    while (__hip_atomic_load(cnt, __ATOMIC_RELAXED, __HIP_MEMORY_SCOPE_AGENT) < target) {
      __builtin_amdgcn_s_sleep(2);
    }
  }
  __syncthreads();
  __builtin_amdgcn_fence(__ATOMIC_ACQUIRE, "agent");
}

__device__ __forceinline__ void store_pair_agent(short* base, float hv, int n) {
  unsigned int lo = (unsigned int)(unsigned short)f2bf(hv);
  unsigned int other = __shfl_xor(lo, 1);
  if (!(n & 1)) {
    unsigned int pack = lo | (other << 16);
    __hip_atomic_store((unsigned int*)base, pack, __ATOMIC_RELAXED, __HIP_MEMORY_SCOPE_AGENT);
  }
}

__global__ __launch_bounds__(64)
void k_diag(float* out, float v) { if (threadIdx.x < 64) out[threadIdx.x] = v; }

__global__ __launch_bounds__(256)
void k_cast(const float* __restrict__ src, short* __restrict__ dst, int n) {
  int i = blockIdx.x * 256 + threadIdx.x;
  if (i < n) dst[i] = f2bf(src[i]);
}

// ===== repack fp32 W[N][ldK] window -> lane-major MFMA B-frag records (bf16) =====
__global__ __launch_bounds__(64)
void k_repack(const float* __restrict__ src, short* __restrict__ dst,
              int ldK, int koff, int nKC) {
  int bid = blockIdx.x;
  int cb = bid / nKC, kc = bid % nKC;
  int lane = threadIdx.x;
  int n = lane & 15, q = lane >> 4;
  const float* s = src + (size_t)(cb * 16 + n) * ldK + koff + kc * 32 + q * 8;
  short8 v;
  #pragma unroll
  for (int j = 0; j < 8; ++j) v[j] = f2bf(s[j]);
  *(short8*)(dst + ((size_t)(cb * nKC + kc) * 64 + lane) * 8) = v;
}

// ===== repack fp32 -> fp8 e4m3 records (weights scaled x16) =====
__global__ __launch_bounds__(64)
void k_repack8(const float* __restrict__ src, unsigned char* __restrict__ dst,
               int ldK, int koff, int nKC) {
  int bid = blockIdx.x;
  int cb = bid / nKC, kc = bid % nKC;
  int lane = threadIdx.x;
  int n = lane & 15, q = lane >> 4;
  const float* s = src + (size_t)(cb * 16 + n) * ldK + koff + kc * 32 + q * 8;
  int lo = 0, hi = 0;
  lo = __builtin_amdgcn_cvt_pk_fp8_f32(16.f * s[0], 16.f * s[1], lo, false);
  lo = __builtin_amdgcn_cvt_pk_fp8_f32(16.f * s[2], 16.f * s[3], lo, true);
  hi = __builtin_amdgcn_cvt_pk_fp8_f32(16.f * s[4], 16.f * s[5], hi, false);
  hi = __builtin_amdgcn_cvt_pk_fp8_f32(16.f * s[6], 16.f * s[7], hi, true);
  int* d = (int*)(dst + ((size_t)(cb * nKC + kc) * 64 + lane) * 8);
  d[0] = lo; d[1] = hi;
}

// ================= K1: forward deterministic GRU (d) =================
__global__ __launch_bounds__(256)
void k_gru_d(const short* __restrict__ xbf, const short* __restrict__ whd,
             const short* __restrict__ wid, const float* __restrict__ bi,
             const float* __restrict__ bh, short* __restrict__ dbuf, int* bar) {
  extern __shared__ short smem[];
  short* whs = smem;                 // [48][1032]
  short* wis = smem + 48 * 1032;     // [48][72]
  const int tid = threadIdx.x;
  const int lane = tid & 63;
  const int w = tid >> 6;
  const int q = lane >> 4, n = lane & 15;
  const int jb = (int)blockIdx.x * 16;

  for (int it = tid; it < 48 * 128; it += 256) {
    int g = it >> 7, kc = (it & 127) * 8;
    int grow = (g < 16) ? (jb + g) : (g < 32) ? (1024 + jb + g - 16) : (2048 + jb + g - 32);
    *(short8*)(&whs[g * 1032 + kc]) = *(const short8*)(whd + (size_t)grow * 1024 + kc);
  }
  for (int it = tid; it < 48 * 8; it += 256) {
    int g = it >> 3, kc = (it & 7) * 8;
    int grow = (g < 16) ? (jb + g) : (g < 32) ? (1024 + jb + g - 16) : (2048 + jb + g - 32);
    *(short8*)(&wis[g * 72 + kc]) = *(const short8*)(wid + (size_t)grow * 64 + kc);
  }
  __syncthreads();

  const int j = jb + n;
  const float bir = bi[j] + bh[j];
  const float biz = bi[1024 + j] + bh[1024 + j];
  const float bin = bi[2048 + j];
  const float bhn = bh[2048 + j];
  const int r = 16 * w + n;

  #pragma unroll 1
  for (int t = 1; t < TT; ++t) {
    const short* hbase = dbuf + (size_t)(t - 1) * BB * RR;
    const short* pa = hbase + (size_t)r * RR + q * 8;
    short8 Areg[32];
    #pragma unroll
    for (int i = 0; i < 32; ++i) Areg[i] = *(const short8*)(pa + 32 * i);
    short8 Xreg[2];
    if (t >= 2) {
      const short* px = xbf + ((size_t)r * TT + (t - 2)) * XX + q * 8;
      Xreg[0] = *(const short8*)(px);
      Xreg[1] = *(const short8*)(px + 32);
    }
    float hp[4];
    #pragma unroll
    for (int reg = 0; reg < 4; ++reg)
      hp[reg] = bf2f(hbase[(size_t)(16 * w + q * 4 + reg) * RR + j]);

    f32x4 ar = fzero(), az = fzero(), anh = fzero(), anu = fzero();
    #pragma unroll
    for (int i = 0; i < 32; ++i) {
      int kb = 32 * i;
      short8 Br = *(const short8*)(&whs[n * 1032 + kb + q * 8]);
      short8 Bz = *(const short8*)(&whs[(16 + n) * 1032 + kb + q * 8]);
      short8 Bn = *(const short8*)(&whs[(32 + n) * 1032 + kb + q * 8]);
      ar = mfma16(Areg[i], Br, ar); az = mfma16(Areg[i], Bz, az); anh = mfma16(Areg[i], Bn, anh);
    }
    if (t >= 2) {
      #pragma unroll
      for (int i = 0; i < 2; ++i) {
        int kb = 32 * i;
        short8 Br = *(const short8*)(&wis[n * 72 + kb + q * 8]);
        short8 Bz = *(const short8*)(&wis[(16 + n) * 72 + kb + q * 8]);
        short8 Bn = *(const short8*)(&wis[(32 + n) * 72 + kb + q * 8]);
        ar = mfma16(Xreg[i], Br, ar); az = mfma16(Xreg[i], Bz, az); anu = mfma16(Xreg[i], Bn, anu);
      }
    }
    #pragma unroll
    for (int reg = 0; reg < 4; ++reg) {
      int m = 16 * w + q * 4 + reg;
      float rg = sigm(ar[reg] + bir);
      float zg = sigm(az[reg] + biz);
      float nn = tanh_(anu[reg] + bin + rg * (anh[reg] + bhn));
      float hv = (1.f - zg) * nn + zg * hp[reg];
      store_pair_agent(&dbuf[(size_t)t * BB * RR + (size_t)m * RR + (j & ~1)], hv, n);
    }
    if (t < TT - 1) fastbar(bar, 64 * t);
  }
}

// ======== K2b: precompute a-GRU input gates (chunk 0 only, 64 steps) =======
__global__ __launch_bounds__(256)
void k_prea(const short* __restrict__ xbf, const short* __restrict__ dbuf,
            const short* __restrict__ ria, const float* __restrict__ bi,
            const int* __restrict__ xsl, short* __restrict__ xgc, int t2base) {
  const int tl = blockIdx.x / 12, ct = blockIdx.x % 12;
  const int t2 = t2base + tl;
  const int tid = threadIdx.x, lane = tid & 63, w = tid >> 6;
  const int q = lane >> 4, n = lane & 15;
  const int cb = ct * 256 + w * 64;
  const int cbr0 = ct * 16 + w * 4;
  const short* pax[4]; const short* pad[4];
  #pragma unroll
  for (int mt = 0; mt < 4; ++mt) {
    int rowb = 16 * mt + n;
    int sl = xsl[rowb];
    int ti = (t2 < sl) ? (sl - 1 - t2) : t2;
    pax[mt] = xbf + ((size_t)rowb * TT + ti) * XX + q * 8;
    pad[mt] = dbuf + ((size_t)ti * BB + rowb) * RR + q * 8;
  }
  f32x4 acc[4][4];
  #pragma unroll
  for (int a = 0; a < 4; ++a)
    #pragma unroll
    for (int b = 0; b < 4; ++b) acc[a][b] = fzero();
  #pragma unroll
  for (int kc = 0; kc < 2; ++kc) {
    short8 Av[4], Bv[4];
    #pragma unroll
    for (int mt = 0; mt < 4; ++mt) Av[mt] = *(const short8*)(pax[mt] + kc * 32);
    #pragma unroll
    for (int nt = 0; nt < 4; ++nt)
      Bv[nt] = *(const short8*)(ria + ((size_t)((cbr0 + nt) * 34 + kc)) * 512 + lane * 8);
    #pragma unroll
    for (int mt = 0; mt < 4; ++mt)
      #pragma unroll
      for (int nt = 0; nt < 4; ++nt) acc[mt][nt] = mfma16(Av[mt], Bv[nt], acc[mt][nt]);
  }
  #pragma unroll 2
  for (int kc = 0; kc < 32; ++kc) {
    short8 Av[4], Bv[4];
    #pragma unroll
    for (int mt = 0; mt < 4; ++mt) Av[mt] = *(const short8*)(pad[mt] + kc * 32);
    #pragma unroll
    for (int nt = 0; nt < 4; ++nt)
      Bv[nt] = *(const short8*)(ria + ((size_t)((cbr0 + nt) * 34 + 2 + kc)) * 512 + lane * 8);
    #pragma unroll
    for (int mt = 0; mt < 4; ++mt)
      #pragma unroll
      for (int nt = 0; nt < 4; ++nt) acc[mt][nt] = mfma16(Av[mt], Bv[nt], acc[mt][nt]);
  }
  #pragma unroll
  for (int mt = 0; mt < 4; ++mt)
    #pragma unroll
    for (int nt = 0; nt < 4; ++nt) {
      int col = cb + 16 * nt + n;
      float bv = bi[col];
      #pragma unroll
      for (int reg = 0; reg < 4; ++reg) {
        int m = 16 * mt + q * 4 + reg;
        xgc[((size_t)tl * BB + m) * 3072 + col] = f2bf(acc[mt][nt][reg] + bv);
      }
    }
}

// ============ K3: a-GRU scan (64-step chunk) + fused prea workers ============
__global__ __launch_bounds__(256)
void k_gru_a2(const short* __restrict__ wha, const float* __restrict__ bh,
              const int* __restrict__ xsl, short* __restrict__ abuf,
              short* __restrict__ ha, const short* __restrict__ xgcA,
              short* __restrict__ xgcB, const short* __restrict__ xbf,
              const short* __restrict__ dbuf, const short* __restrict__ ria,
              const float* __restrict__ bia,
              int t2base, int nextbase, int* bar) {
  extern __shared__ short smem[];
  short* whs = smem;                 // [48][1032] (scan role only)
  const int tid = threadIdx.x;
  const int lane = tid & 63;
  const int w = tid >> 6;
  const int q = lane >> 4, n = lane & 15;
  const int bid = (int)blockIdx.x;

  if (bid >= 64) {
    // ---------------- worker role: prea for next chunk ----------------
    if (nextbase >= TT) return;
    const int wb = bid - 64;           // 0..191
    #pragma unroll 1
    for (int u = 0; u < 4; ++u) {
      const int unit = wb * 4 + u;     // 0..767
      const int tl = unit / 12, ct = unit % 12;
      const int t2 = nextbase + tl;
      const int cb = ct * 256 + w * 64;
      const int cbr0 = ct * 16 + w * 4;
      const short* pax[4]; const short* pad[4];
      #pragma unroll
      for (int mt = 0; mt < 4; ++mt) {
        int rowb = 16 * mt + n;
        int sl = xsl[rowb];
        int ti = (t2 < sl) ? (sl - 1 - t2) : t2;
        pax[mt] = xbf + ((size_t)rowb * TT + ti) * XX + q * 8;
        pad[mt] = dbuf + ((size_t)ti * BB + rowb) * RR + q * 8;
      }
      f32x4 acc[4][4];
      #pragma unroll
      for (int a = 0; a < 4; ++a)
        #pragma unroll
        for (int b = 0; b < 4; ++b) acc[a][b] = fzero();
      #pragma unroll
      for (int kc = 0; kc < 2; ++kc) {
        short8 Av[4], Bv[4];
        #pragma unroll
        for (int mt = 0; mt < 4; ++mt) Av[mt] = *(const short8*)(pax[mt] + kc * 32);
        #pragma unroll
        for (int nt = 0; nt < 4; ++nt)
          Bv[nt] = *(const short8*)(ria + ((size_t)((cbr0 + nt) * 34 + kc)) * 512 + lane * 8);
        #pragma unroll
        for (int mt = 0; mt < 4; ++mt)
          #pragma unroll
          for (int nt = 0; nt < 4; ++nt) acc[mt][nt] = mfma16(Av[mt], Bv[nt], acc[mt][nt]);
      }
      #pragma unroll 2
      for (int kc = 0; kc < 32; ++kc) {
        short8 Av[4], Bv[4];
        #pragma unroll
        for (int mt = 0; mt < 4; ++mt) Av[mt] = *(const short8*)(pad[mt] + kc * 32);
        #pragma unroll
        for (int nt = 0; nt < 4; ++nt)
          Bv[nt] = *(const short8*)(ria + ((size_t)((cbr0 + nt) * 34 + 2 + kc)) * 512 + lane * 8);
        #pragma unroll
        for (int mt = 0; mt < 4; ++mt)
          #pragma unroll
          for (int nt = 0; nt < 4; ++nt) acc[mt][nt] = mfma16(Av[mt], Bv[nt], acc[mt][nt]);
      }
      #pragma unroll
      for (int mt = 0; mt < 4; ++mt)
        #pragma unroll
        for (int nt = 0; nt < 4; ++nt) {
          int col = cb + 16 * nt + n;
          float bv = bia[col];
          #pragma unroll
          for (int reg = 0; reg < 4; ++reg) {
            int m = 16 * mt + q * 4 + reg;
            xgcB[((size_t)tl * BB + m) * 3072 + col] = f2bf(acc[mt][nt][reg] + bv);
          }
        }
    }
    return;
  }

  // ---------------- scan role (blocks 0..63) ----------------
  const int jb = bid * 16;
  for (int it = tid; it < 48 * 128; it += 256) {
    int g = it >> 7, kc = (it & 127) * 8;
    int grow = (g < 16) ? (jb + g) : (g < 32) ? (1024 + jb + g - 16) : (2048 + jb + g - 32);
    *(short8*)(&whs[g * 1032 + kc]) = *(const short8*)(wha + (size_t)grow * 1024 + kc);
  }
  __syncthreads();

  const int j = jb + n;
  const float bhr = bh[j];
  const float bhz = bh[1024 + j];
  const float bhn = bh[2048 + j];
  const int r = 16 * w + n;
  int sle[4];
  #pragma unroll
  for (int reg = 0; reg < 4; ++reg) sle[reg] = xsl[16 * w + q * 4 + reg];

  #pragma unroll 1
  for (int tl = 0; tl < 64; ++tl) {
    const int t2 = t2base + tl;
    int par = t2 & 1;
    const short* hbase = ha + (size_t)par * BB * RR;
    const short* pa = hbase + (size_t)r * RR + q * 8;
    short8 Areg[32];
    #pragma unroll
    for (int i = 0; i < 32; ++i) Areg[i] = *(const short8*)(pa + 32 * i);
    const short* xgs = xgcA + (size_t)tl * BB * 3072;
    float xr[4], xz[4], xn[4], hp[4];
    #pragma unroll
    for (int reg = 0; reg < 4; ++reg) {
      int m = 16 * w + q * 4 + reg;
      xr[reg] = bf2f(xgs[(size_t)m * 3072 + j]);
      xz[reg] = bf2f(xgs[(size_t)m * 3072 + 1024 + j]);
      xn[reg] = bf2f(xgs[(size_t)m * 3072 + 2048 + j]);
      hp[reg] = bf2f(hbase[(size_t)m * RR + j]);
    }
    f32x4 hr = fzero(), hz = fzero(), hn = fzero();
    #pragma unroll
    for (int i = 0; i < 32; ++i) {
      int kb = 32 * i;
      short8 Br = *(const short8*)(&whs[n * 1032 + kb + q * 8]);
      short8 Bz = *(const short8*)(&whs[(16 + n) * 1032 + kb + q * 8]);
      short8 Bn = *(const short8*)(&whs[(32 + n) * 1032 + kb + q * 8]);
      hr = mfma16(Areg[i], Br, hr); hz = mfma16(Areg[i], Bz, hz); hn = mfma16(Areg[i], Bn, hn);
    }
    #pragma unroll
    for (int reg = 0; reg < 4; ++reg) {
      int m = 16 * w + q * 4 + reg;
      int slm = sle[reg];
      int tie = (t2 < slm) ? (slm - 1 - t2) : t2;
      float rg = sigm(xr[reg] + hr[reg] + bhr);
      float ug = sigm(xz[reg] + hz[reg] + bhz);
      float nn = tanh_(xn[reg] + rg * (hn[reg] + bhn));
      float hv = (1.f - ug) * nn + ug * hp[reg];
      store_pair_agent(&ha[(size_t)(par ^ 1) * BB * RR + (size_t)m * RR + (j & ~1)], hv, n);
      store_pair_agent(&abuf[((size_t)tie * BB + m) * RR + (j & ~1)], hv, n);
    }
    if (tl < 63) fastbar(bar, 64 * (tl + 1));
  }
}

// ================= K4: pre1q = a @ Wq1[:, :1024]^T + bq1 ============
__global__ __launch_bounds__(256)
void k_pre1(const short* __restrict__ abuf, const short* __restrict__ rq1d,
            const float* __restrict__ bq1, short* __restrict__ pre1) {
  const int tid = threadIdx.x, lane = tid & 63, w = tid >> 6;
  const int q = lane >> 4, n = lane & 15;
  const int rt = blockIdx.x >> 1, ct = blockIdx.x & 1;
  const int cb = ct * 256 + w * 64;
  const int cbr0 = ct * 16 + w * 4;
  f32x4 acc[4][4];
  #pragma unroll
  for (int a = 0; a < 4; ++a)
    #pragma unroll
    for (int b = 0; b < 4; ++b) acc[a][b] = fzero();
  const short* pa = abuf + (size_t)(rt * 64) * RR;
  #pragma unroll 2
  for (int kc = 0; kc < 32; ++kc) {
    short8 Av[4], Bv[4];
    #pragma unroll
    for (int mt = 0; mt < 4; ++mt)
      Av[mt] = *(const short8*)(pa + (size_t)(16 * mt + n) * RR + kc * 32 + q * 8);
    #pragma unroll
    for (int nt = 0; nt < 4; ++nt)
      Bv[nt] = *(const short8*)(rq1d + ((size_t)((cbr0 + nt) * 32 + kc)) * 512 + lane * 8);
    #pragma unroll
    for (int mt = 0; mt < 4; ++mt)
      #pragma unroll
      for (int nt = 0; nt < 4; ++nt)
        acc[mt][nt] = mfma16(Av[mt], Bv[nt], acc[mt][nt]);
  }
  #pragma unroll
  for (int mt = 0; mt < 4; ++mt)
    #pragma unroll
    for (int nt = 0; nt < 4; ++nt) {
      int h = cb + 16 * nt + n;
      float bqv = bq1[h];
      #pragma unroll
      for (int reg = 0; reg < 4; ++reg) {
        int row = rt * 64 + 16 * mt + q * 4 + reg;
        pre1[(size_t)row * HH + h] = f2bf(acc[mt][nt][reg] + bqv);
      }
    }
}

// ====== K5: latent q scan — fp8 weights/activations (R2-proven) ======
__global__ __launch_bounds__(1024)
void k_qscan(const short* __restrict__ pre1,
             const unsigned char* __restrict__ rq1z8,
             const unsigned char* __restrict__ rq28,
             const unsigned char* __restrict__ rq38,
             const unsigned char* __restrict__ rqg8,
             const float* __restrict__ bq2,
             const float* __restrict__ bq3, const float* __restrict__ bqg,
             const float* __restrict__ eps,
             short* __restrict__ zbf, float* __restrict__ qmu, float* __restrict__ qsd) {
  extern __shared__ unsigned char dsm8[];
  unsigned char* zs8 = dsm8;                   // [16][136] fp8 (z x8)
  unsigned char* hA8 = dsm8 + 2176;            // [16][520] fp8 (act x8)
  unsigned char* hB8 = dsm8 + 10496;           // [16][520] fp8
  float* gs = (float*)(dsm8 + 10496);          // [16][264] f32 overlays hB8 (disjoint lifetime)
  const int tid = threadIdx.x, lane = tid & 63, w = tid >> 6;   // w: 0..15
  const int q = lane >> 4, n = lane & 15;
  const int qb = blockIdx.x;
  unsigned char* w2s = dsm8 + 27392 + w * 8192; // 16 staged RQ2 records per wave
  const float INV128 = 0.0078125f;

  for (int i = tid; i < 2176; i += 1024) zs8[i] = 0;

  const unsigned char* r2a8 = rq28 + (size_t)(2 * w * 16) * 512 + lane * 8;
  const unsigned char* r3a8 = rq38 + (size_t)(2 * w * 16) * 512 + lane * 8;
  const unsigned char* rga8 = rqg8 + (size_t)(w * 16) * 512 + lane * 8;

  // stage this wave's RQ2 records kc=0..7 (a0 and a1) into wave-private LDS
  {
    const unsigned char* s0 = rq28 + (size_t)(2 * w * 16) * 512;
    #pragma unroll
    for (int s = 0; s < 8; ++s)
      *(i64t*)(w2s + s * 512 + lane * 8) = *(const i64t*)(s0 + (size_t)s * 512 + lane * 8);
    #pragma unroll
    for (int s = 0; s < 8; ++s)
      *(i64t*)(w2s + (8 + s) * 512 + lane * 8) = *(const i64t*)(s0 + (size_t)(16 + s) * 512 + lane * 8);
  }
  // register-resident: full W1z slice (8 recs = 16 VGPRs)
  i64t B1[8];
  {
    const unsigned char* b1a = rq1z8 + (size_t)(2 * w * 4) * 512 + lane * 8;
    #pragma unroll
    for (int i = 0; i < 4; ++i) {
      B1[i * 2]     = *(const i64t*)(b1a + i * 512);
      B1[i * 2 + 1] = *(const i64t*)(b1a + 2048 + i * 512);
    }
  }
  // register-resident: RQ3 records kc=0..7 for a0 and a1 (16 recs = 32 VGPRs)
  i64t R3a[8], R3b[8];
  #pragma unroll
  for (int k2 = 0; k2 < 8; ++k2) {
    R3a[k2] = *(const i64t*)(r3a8 + k2 * 512);
    R3b[k2] = *(const i64t*)(r3a8 + 8192 + k2 * 512);
  }

  // pre1 / eps prefetch pointers
  const size_t P1T = (size_t)BB * HH;
  const short* p1b = pre1 + (size_t)(qb * 16 + q * 4) * HH + w * 32 + n;
  short p1r[8];
  #pragma unroll
  for (int nt = 0; nt < 2; ++nt)
    #pragma unroll
    for (int rg2 = 0; rg2 < 4; ++rg2)
      p1r[nt * 4 + rg2] = p1b[(size_t)rg2 * HH + nt * 16];
  const float* ep0 = eps + (size_t)(qb * 16 + (tid >> 7)) * ZZ + (tid & 127);
  const float* ep1 = ep0 + (size_t)8 * ZZ;
  __syncthreads();

  #pragma unroll 1
  for (int t = 0; t < TT; ++t) {
    float e0 = ep0[(size_t)t * (BB * ZZ)];
    float e1 = ep1[(size_t)t * (BB * ZZ)];
    float p1v[2][4];
    #pragma unroll
    for (int nt = 0; nt < 2; ++nt)
      #pragma unroll
      for (int rg2 = 0; rg2 < 4; ++rg2)
        p1v[nt][rg2] = bf2f(p1r[nt * 4 + rg2]);
    short p1n[8];
    if (t + 1 < TT) {
      const short* pb = p1b + (size_t)(t + 1) * P1T;
      #pragma unroll
      for (int nt = 0; nt < 2; ++nt)
        #pragma unroll
        for (int rg2 = 0; rg2 < 4; ++rg2)
          p1n[nt * 4 + rg2] = pb[(size_t)rg2 * HH + nt * 16];
    }
    // ---- L1: z-part from register-resident B1 (fp8) ----
    {
      f32x4 a0 = fzero(), a1 = fzero();
      #pragma unroll
      for (int i = 0; i < 4; ++i) {
        i64t A = *(const i64t*)(zs8 + n * 136 + i * 32 + q * 8);
        a0 = mfma8(A, B1[i * 2], a0);
        a1 = mfma8(A, B1[i * 2 + 1], a1);
      }
      #pragma unroll
      for (int nt = 0; nt < 2; ++nt) {
        f32x4 av = nt ? a1 : a0;
        int colb = w * 32 + nt * 16;
        #pragma unroll
        for (int rg2 = 0; rg2 < 4; ++rg2) {
          float val = lrelu(av[rg2] * INV128 + p1v[nt][rg2]);
          st4_fp8(hA8 + (q * 4 + rg2) * 520 + colb + (n & ~3), 8.f * val, n);
        }
      }
    }
    __syncthreads();
    // ---- L2: kc 0..7 from LDS-staged records, kc 8..15 streamed ----
    {
      f32x4 a0 = fzero(), a1 = fzero();
      #pragma unroll 1
      for (int c = 0; c < 4; ++c) {
        i64t Br[8];
        if (c < 2) {
          #pragma unroll
          for (int i = 0; i < 4; ++i) {
            Br[i * 2]     = *(const i64t*)(w2s + (c * 4 + i) * 512 + lane * 8);
            Br[i * 2 + 1] = *(const i64t*)(w2s + (8 + c * 4 + i) * 512 + lane * 8);
          }
        } else {
          #pragma unroll
          for (int i = 0; i < 4; ++i) {
            Br[i * 2]     = *(const i64t*)(r2a8 + (c * 4 + i) * 512);
            Br[i * 2 + 1] = *(const i64t*)(r2a8 + 8192 + (c * 4 + i) * 512);
          }
        }
        #pragma unroll
        for (int i = 0; i < 4; ++i) {
          i64t A = *(const i64t*)(hA8 + n * 520 + c * 128 + i * 32 + q * 8);
          a0 = mfma8(A, Br[i * 2], a0);
          a1 = mfma8(A, Br[i * 2 + 1], a1);
        }
      }
      #pragma unroll
      for (int nt = 0; nt < 2; ++nt) {
        f32x4 av = nt ? a1 : a0;
        int h = w * 32 + nt * 16 + n;
        float bv = bq2[h];
        int colb = w * 32 + nt * 16;
        #pragma unroll
        for (int rg2 = 0; rg2 < 4; ++rg2) {
          float val = lrelu(av[rg2] * INV128 + bv);
          st4_fp8(hB8 + (q * 4 + rg2) * 520 + colb + (n & ~3), 8.f * val, n);
        }
      }
    }
    __syncthreads();
    // ---- L3: kc 0..7 from registers, kc 8..15 streamed ----
    {
      f32x4 a0 = fzero(), a1 = fzero();
      #pragma unroll 1
      for (int c = 0; c < 4; ++c) {
        i64t Br[8];
        if (c < 2) {
          #pragma unroll
          for (int i = 0; i < 4; ++i) {
            Br[i * 2]     = R3a[c * 4 + i];
            Br[i * 2 + 1] = R3b[c * 4 + i];
          }
        } else {
          #pragma unroll
          for (int i = 0; i < 4; ++i) {
            Br[i * 2]     = *(const i64t*)(r3a8 + (c * 4 + i) * 512);
            Br[i * 2 + 1] = *(const i64t*)(r3a8 + 8192 + (c * 4 + i) * 512);
          }
        }
        #pragma unroll
        for (int i = 0; i < 4; ++i) {
          i64t A = *(const i64t*)(hB8 + n * 520 + c * 128 + i * 32 + q * 8);
          a0 = mfma8(A, Br[i * 2], a0);
          a1 = mfma8(A, Br[i * 2 + 1], a1);
        }
      }
      #pragma unroll
      for (int nt = 0; nt < 2; ++nt) {
        f32x4 av = nt ? a1 : a0;
        int h = w * 32 + nt * 16 + n;
        float bv = bq3[h];
        int colb = w * 32 + nt * 16;
        #pragma unroll
        for (int rg2 = 0; rg2 < 4; ++rg2) {
          float val = lrelu(av[rg2] * INV128 + bv);
          st4_fp8(hA8 + (q * 4 + rg2) * 520 + colb + (n & ~3), 8.f * val, n);
        }
      }
    }
    __syncthreads();
    // ---- Gauss head (streamed; gs overlays hB8 — hB8 dead here) ----
    {
      f32x4 ga = fzero();
      #pragma unroll 1
      for (int c = 0; c < 4; ++c) {
        i64t Br[4];
        #pragma unroll
        for (int i = 0; i < 4; ++i) Br[i] = *(const i64t*)(rga8 + (c * 4 + i) * 512);
        #pragma unroll
        for (int i = 0; i < 4; ++i) {
          i64t A = *(const i64t*)(hA8 + n * 520 + c * 128 + i * 32 + q * 8);
          ga = mfma8(A, Br[i], ga);
        }
      }
      int gc = w * 16 + n;
      float bv = bqg[gc];
      #pragma unroll
      for (int rg2 = 0; rg2 < 4; ++rg2) {
        float o = ga[rg2] * INV128 + bv;
        gs[(q * 4 + rg2) * 264 + gc] = (gc < 128) ? o : splus(o);
      }
    }
    __syncthreads();
    // ---- z update (prefetched eps) ----
    {
      int m0 = tid >> 7, zi0 = tid & 127;
      size_t off0 = ((size_t)t * BB + qb * 16 + m0) * ZZ + zi0;
      size_t off1 = off0 + (size_t)8 * ZZ;
      float mu0 = gs[m0 * 264 + zi0], sd0 = gs[m0 * 264 + 128 + zi0];
      float mu1 = gs[(m0 + 8) * 264 + zi0], sd1 = gs[(m0 + 8) * 264 + 128 + zi0];
      float zv0 = mu0 + sd0 * e0;
      float zv1 = mu1 + sd1 * e1;
      st4_fp8(zs8 + m0 * 136 + (zi0 & ~3), 8.f * zv0, zi0 & 15);
      st4_fp8(zs8 + (m0 + 8) * 136 + (zi0 & ~3), 8.f * zv1, zi0 & 15);
      zbf[off0] = f2bf(zv0); zbf[off1] = f2bf(zv1);
      qmu[off0] = mu0; qmu[off1] = mu1;
      qsd[off0] = sd0; qsd[off1] = sd1;
    }
    __syncthreads();
    if (t + 1 < TT) {
      #pragma unroll
      for (int k2 = 0; k2 < 8; ++k2) p1r[k2] = p1n[k2];
    }
  }
}

// ========== K6: p-net + decoder + KL/logprob (repacked B) ==========
__global__ __launch_bounds__(256)
void k_pnet(const short* __restrict__ dbuf, const short* __restrict__ zbf,
            const short* __restrict__ rp1, const short* __restrict__ rp2,
            const short* __restrict__ rp3, const short* __restrict__ rpg,
            const short* __restrict__ rdd,
            const float* __restrict__ bp1, const float* __restrict__ bp2,
            const float* __restrict__ bp3, const float* __restrict__ bpg,
            const float* __restrict__ bdd,
            const float* __restrict__ qmu, const float* __restrict__ qsd,
            const float* __restrict__ x, const int* __restrict__ xsl,
            float* __restrict__ lp_acc, float* __restrict__ kl_acc) {
  __shared__ short bufA[32 * 512];
  __shared__ short bufB[32 * 512];
  const int t = blockIdx.x >> 1, half = blockIdx.x & 1;
  const int tid = threadIdx.x, lane = tid & 63, w = tid >> 6;
  const int q = lane >> 4, n = lane & 15;
  const int rg = w & 1, cgp = w >> 1;
  const int rl = 16 * rg + n;
  const int rA = 32 * half + rl;
  const int ml0 = 16 * rg + q * 4;
  const int b0 = 32 * half + ml0;
  const short* dA = dbuf + ((size_t)t * BB + rA) * RR + q * 8;

  // ---- L1: [d_t ; z_{t-1}] @ Wp1^T -> bufA ----
  #pragma unroll 1
  for (int ch = 0; ch < 2; ++ch) {
    const int hbase = cgp * 256 + ch * 128;
    const int cbr0 = cgp * 16 + ch * 8;
    f32x4 acc[8];
    #pragma unroll
    for (int i = 0; i < 8; ++i) acc[i] = fzero();
    #pragma unroll 2
    for (int kc = 0; kc < 32; ++kc) {
      short8 A = *(const short8*)(dA + kc * 32);
      #pragma unroll
      for (int nt = 0; nt < 8; ++nt) {
        short8 Bv = *(const short8*)(rp1 + ((size_t)((cbr0 + nt) * 36 + kc)) * 512 + lane * 8);
        acc[nt] = mfma16(A, Bv, acc[nt]);
      }
    }
    if (t > 0) {
      const short* zAp = zbf + ((size_t)(t - 1) * BB + rA) * ZZ + q * 8;
      #pragma unroll
      for (int kc = 0; kc < 4; ++kc) {
        short8 A = *(const short8*)(zAp + kc * 32);
        #pragma unroll
        for (int nt = 0; nt < 8; ++nt) {
          short8 Bv = *(const short8*)(rp1 + ((size_t)((cbr0 + nt) * 36 + 32 + kc)) * 512 + lane * 8);
          acc[nt] = mfma16(A, Bv, acc[nt]);
        }
      }
    }
    #pragma unroll
    for (int nt = 0; nt < 8; ++nt) {
      int h = hbase + nt * 16 + n;
      float bv = bp1[h];
      #pragma unroll
      for (int reg = 0; reg < 4; ++reg)
        bufA[sw(ml0 + reg, h)] = f2bf(lrelu(acc[nt][reg] + bv));
    }
  }
  __syncthreads();
  // ---- L2 ----
  #pragma unroll 1
  for (int ch = 0; ch < 2; ++ch) {
    const int hbase = cgp * 256 + ch * 128;
    const int cbr0 = cgp * 16 + ch * 8;
    f32x4 acc[8];
    #pragma unroll
    for (int i = 0; i < 8; ++i) acc[i] = fzero();
    #pragma unroll 2
    for (int kc = 0; kc < 16; ++kc) {
      short8 A = *(const short8*)(&bufA[sw(rl, kc * 32 + q * 8)]);
      #pragma unroll
      for (int nt = 0; nt < 8; ++nt) {
        short8 Bv = *(const short8*)(rp2 + ((size_t)((cbr0 + nt) * 16 + kc)) * 512 + lane * 8);
        acc[nt] = mfma16(A, Bv, acc[nt]);
      }
    }
    #pragma unroll
    for (int nt = 0; nt < 8; ++nt) {
      int h = hbase + nt * 16 + n;
      float bv = bp2[h];
      #pragma unroll
      for (int reg = 0; reg < 4; ++reg)
        bufB[sw(ml0 + reg, h)] = f2bf(lrelu(acc[nt][reg] + bv));
    }
  }
  __syncthreads();
  // ---- L3 ----
  #pragma unroll 1
  for (int ch = 0; ch < 2; ++ch) {
    const int hbase = cgp * 256 + ch * 128;
    const int cbr0 = cgp * 16 + ch * 8;
    f32x4 acc[8];
    #pragma unroll
    for (int i = 0; i < 8; ++i) acc[i] = fzero();
    #pragma unroll 2
    for (int kc = 0; kc < 16; ++kc) {
      short8 A = *(const short8*)(&bufB[sw(rl, kc * 32 + q * 8)]);
      #pragma unroll
      for (int nt = 0; nt < 8; ++nt) {
        short8 Bv = *(const short8*)(rp3 + ((size_t)((cbr0 + nt) * 16 + kc)) * 512 + lane * 8);
        acc[nt] = mfma16(A, Bv, acc[nt]);
      }
    }
    #pragma unroll
    for (int nt = 0; nt < 8; ++nt) {
      int h = hbase + nt * 16 + n;
      float bv = bp3[h];
      #pragma unroll
      for (int reg = 0; reg < 4; ++reg)
        bufA[sw(ml0 + reg, h)] = f2bf(lrelu(acc[nt][reg] + bv));
    }
  }
  __syncthreads();
  // ---- Gauss head ----
  f32x4 acc[8];
  #pragma unroll
  for (int i = 0; i < 8; ++i) acc[i] = fzero();
  #pragma unroll 2
  for (int kc = 0; kc < 16; ++kc) {
    short8 A = *(const short8*)(&bufA[sw(rl, kc * 32 + q * 8)]);
    #pragma unroll
    for (int nt = 0; nt < 8; ++nt) {
      short8 Bv = *(const short8*)(rpg + ((size_t)((cgp * 8 + nt) * 16 + kc)) * 512 + lane * 8);
      acc[nt] = mfma16(A, Bv, acc[nt]);
    }
  }
  float* gs = (float*)bufB;
  if (cgp == 0) {
    #pragma unroll
    for (int nt = 0; nt < 8; ++nt) {
      int zi = nt * 16 + n;
      float bv = bpg[zi];
      #pragma unroll
      for (int reg = 0; reg < 4; ++reg)
        gs[(ml0 + reg) * 128 + zi] = acc[nt][reg] + bv;
    }
  }
  __syncthreads();
  if (cgp == 1) {
    float kls[4] = {0.f, 0.f, 0.f, 0.f};
    #pragma unroll
    for (int nt = 0; nt < 8; ++nt) {
      int zi = nt * 16 + n;
      float bv = bpg[128 + zi];
      #pragma unroll
      for (int reg = 0; reg < 4; ++reg) {
        int b = b0 + reg;
        float ps = splus(acc[nt][reg] + bv);
        float pm = gs[(ml0 + reg) * 128 + zi];
        size_t off = ((size_t)t * BB + b) * ZZ + zi;
        float qm = qmu[off], qs = qsd[off];
        float dd = qm - pm;
        kls[reg] += __logf(ps / qs) + (qs * qs + dd * dd) / (2.f * ps * ps) - 0.5f;
      }
    }
    #pragma unroll
    for (int reg = 0; reg < 4; ++reg) {
      float v = kls[reg];
      v += __shfl_xor(v, 1); v += __shfl_xor(v, 2); v += __shfl_xor(v, 4); v += __shfl_xor(v, 8);
      if (n == 0) {
        int b = b0 + reg;
        if (t < xsl[b]) atomicAdd(kl_acc + b, v);
      }
    }
  }
  // ---- decoder ----
  f32x4 dacc[2];
  dacc[0] = fzero(); dacc[1] = fzero();
  {
    const short* zA = zbf + ((size_t)t * BB + rA) * ZZ + q * 8;
    #pragma unroll
    for (int kc = 0; kc < 4; ++kc) {
      short8 A = *(const short8*)(zA + kc * 32);
      #pragma unroll
      for (int nt = 0; nt < 2; ++nt) {
        short8 Bv = *(const short8*)(rdd + ((size_t)((cgp * 2 + nt) * 36 + kc)) * 512 + lane * 8);
        dacc[nt] = mfma16(A, Bv, dacc[nt]);
      }
    }
    #pragma unroll 2
    for (int kc = 0; kc < 32; ++kc) {
      short8 A = *(const short8*)(dA + kc * 32);
      #pragma unroll
      for (int nt = 0; nt < 2; ++nt) {
        short8 Bv = *(const short8*)(rdd + ((size_t)((cgp * 2 + nt) * 36 + 4 + kc)) * 512 + lane * 8);
        dacc[nt] = mfma16(A, Bv, dacc[nt]);
      }
    }
  }
  float lps[4] = {0.f, 0.f, 0.f, 0.f};
  #pragma unroll
  for (int nt = 0; nt < 2; ++nt) {
    int xi = cgp * 32 + nt * 16 + n;
    float bv = bdd[xi];
    #pragma unroll
    for (int reg = 0; reg < 4; ++reg) {
      int b = b0 + reg;
      float mu = dacc[nt][reg] + bv;
      float xv = x[((size_t)b * TT + t) * XX + xi];
      float e = xv - mu;
      lps[reg] += -0.5f * (e * e + 1.8378770664093453f);
    }
  }
  #pragma unroll
  for (int reg = 0; reg < 4; ++reg) {
    float v = lps[reg];
    v += __shfl_xor(v, 1); v += __shfl_xor(v, 2); v += __shfl_xor(v, 4); v += __shfl_xor(v, 8);
    if (n == 0) {
      int b = b0 + reg;
      if (t < xsl[b]) atomicAdd(lp_acc + b, v);
    }
  }
}

__global__ __launch_bounds__(64)
void k_final(const float* __restrict__ lp, const float* __restrict__ kl, float* __restrict__ out) {
  int b = threadIdx.x;
  if (b < BB) out[b] = lp[b] - kl[b];
}

extern "C" void kernel_launch(void* const* d_in, const int* in_sizes, int n_in,
                              void* d_out, int out_size, void* d_ws, size_t ws_size,
                              hipStream_t stream) {
  if (ws_size < WS_NEED) {
    k_diag<<<1, 64, 0, stream>>>((float*)d_out, (float)ws_size);
    return;
  }
  const float* x    = (const float*)d_in[0];
  const float* eps  = (const float*)d_in[1];
  const float* Wi_d = (const float*)d_in[2];
  const float* Wh_d = (const float*)d_in[3];
  const float* bi_d = (const float*)d_in[4];
  const float* bh_d = (const float*)d_in[5];
  const float* Wi_a = (const float*)d_in[6];
  const float* Wh_a = (const float*)d_in[7];
  const float* bi_a = (const float*)d_in[8];
  const float* bh_a = (const float*)d_in[9];
  const float* Wq1 = (const float*)d_in[10]; const float* bq1 = (const float*)d_in[11];
  const float* Wq2 = (const float*)d_in[12]; const float* bq2 = (const float*)d_in[13];
  const float* Wq3 = (const float*)d_in[14]; const float* bq3 = (const float*)d_in[15];
  const float* Wqg = (const float*)d_in[16]; const float* bqg = (const float*)d_in[17];
  const float* Wp1 = (const float*)d_in[18]; const float* bp1 = (const float*)d_in[19];
  const float* Wp2 = (const float*)d_in[20]; const float* bp2 = (const float*)d_in[21];
  const float* Wp3 = (const float*)d_in[22]; const float* bp3 = (const float*)d_in[23];
  const float* Wpg = (const float*)d_in[24]; const float* bpg = (const float*)d_in[25];
  const float* Wd  = (const float*)d_in[26]; const float* bd  = (const float*)d_in[27];
  const int*   xsl = (const int*)d_in[28];

  char* ws = (char*)d_ws;
  short* WID  = (short*)(ws + OFF_WID);
  short* WHD  = (short*)(ws + OFF_WHD);
  short* RIA  = (short*)(ws + OFF_WIA);
  short* WHA  = (short*)(ws + OFF_WHA);
  short* RQ1D = (short*)(ws + OFF_WQ1);
  // fp8 q-net weights overlay the RQ1D region once k_pre1 has consumed it
  unsigned char* RQ28  = (unsigned char*)(ws + OFF_WQ1);            // 262144 B
  unsigned char* RQ38  = (unsigned char*)(ws + OFF_WQ1 + 262144UL); // 262144 B
  unsigned char* RQG8  = (unsigned char*)(ws + OFF_WQ1 + 524288UL); // 131072 B
  unsigned char* RQ1Z8 = (unsigned char*)(ws + OFF_WQ1 + 655360UL); // 65536 B
  short* RP1  = (short*)(ws + OFF_WP1);
  short* RP2  = (short*)(ws + OFF_WP2);
  short* RP3  = (short*)(ws + OFF_WP3);
  short* RPG  = (short*)(ws + OFF_WPG);
  short* RD   = (short*)(ws + OFF_WD);
  short* XBF  = (short*)(ws + OFF_XBF);
  short* DBUF = (short*)(ws + OFF_D);
  short* ABUF = (short*)(ws + OFF_A);
  short* PRE1 = (short*)(ws + OFF_PRE1);
  short* XGC0 = (short*)(ws + OFF_PRE1);
  short* XGC1 = (short*)(ws + OFF_PRE1 + XGC_HALF);
  short* ZBF  = (short*)(ws + OFF_ZBF);
  float* QMU  = (float*)(ws + OFF_QMU);
  float* QSD  = (float*)(ws + OFF_QSD);
  short* HA   = (short*)(ws + OFF_HA);
  float* LP   = (float*)(ws + OFF_ACC);
  float* KL   = (float*)(ws + OFF_ACC + 256);
  int*   BAR_D = (int*)(ws + OFF_PRE1);    // free during gru_d
  int*   BAR_A = (int*)(ws + OFF_QSD);     // free during a-chunks

  hipMemsetAsync(ws + OFF_ACC, 0, 512, stream);
  hipMemsetAsync(ws + OFF_HA, 0, 262144, stream);
  hipMemsetAsync(ws + OFF_D, 0, 131072, stream);
  hipMemsetAsync(ws + OFF_PRE1, 0, 64, stream);    // BAR_D

  auto cast = [&](const float* s, short* d, int nel) {
    k_cast<<<(nel + 255) / 256, 256, 0, stream>>>(s, d, nel);
  };
  cast(Wi_d, WID, 3072 * 64);
  cast(Wh_d, WHD, 3072 * 1024);
  cast(Wh_a, WHA, 3072 * 1024);
  cast(x,   XBF,  64 * 512 * 64);

  // lane-major repacks (targets disjoint from their fp32 sources)
  k_repack<<<192 * 34, 64, 0, stream>>>(Wi_a, RIA, 1088, 0, 34);
  k_repack<<<32 * 32, 64, 0, stream>>>(Wq1, RQ1D, 1152, 0, 32);
  k_repack<<<32 * 36, 64, 0, stream>>>(Wp1, RP1, 1152, 0, 36);
  k_repack<<<32 * 16, 64, 0, stream>>>(Wp2, RP2, 512, 0, 16);
  k_repack<<<32 * 16, 64, 0, stream>>>(Wp3, RP3, 512, 0, 16);
  k_repack<<<16 * 16, 64, 0, stream>>>(Wpg, RPG, 512, 0, 16);
  k_repack<<<4 * 36, 64, 0, stream>>>(Wd, RD, 1152, 0, 36);

  hipFuncSetAttribute((const void*)k_gru_d, hipFuncAttributeMaxDynamicSharedMemorySize, 160 * 1024);
  hipFuncSetAttribute((const void*)k_gru_a2, hipFuncAttributeMaxDynamicSharedMemorySize, 160 * 1024);
  hipFuncSetAttribute((const void*)k_qscan, hipFuncAttributeMaxDynamicSharedMemorySize, 160 * 1024);

  {
    void* args[] = { (void*)&XBF, (void*)&WHD, (void*)&WID, (void*)&bi_d,
                     (void*)&bh_d, (void*)&DBUF, (void*)&BAR_D };
    hipLaunchCooperativeKernel((const void*)k_gru_d, dim3(64), dim3(256), args,
                               48 * 1032 * 2 + 48 * 72 * 2, stream);
  }

  // chunk 0 input gates (64 steps) into XGC0
  k_prea<<<64 * 12, 256, 0, stream>>>(XBF, DBUF, RIA, bi_a, xsl, XGC0, 0);

  // 8 fused launches: blocks 0-63 scan chunk c; blocks 64-255 prea chunk c+1
  for (int c = 0; c < 8; ++c) {
    hipMemsetAsync(ws + OFF_QSD, 0, 64, stream);   // reset BAR_A per chunk
    int base = c * 64;
    int nb = base + 64;
    short* xa = (c & 1) ? XGC1 : XGC0;
    short* xb = (c & 1) ? XGC0 : XGC1;
    void* args[] = { (void*)&WHA, (void*)&bh_a, (void*)&xsl, (void*)&ABUF,
                     (void*)&HA, (void*)&xa, (void*)&xb, (void*)&XBF,
                     (void*)&DBUF, (void*)&RIA, (void*)&bi_a,
                     (void*)&base, (void*)&nb, (void*)&BAR_A };
    hipLaunchCooperativeKernel((const void*)k_gru_a2, dim3(256), dim3(256), args,
                               48 * 1032 * 2, stream);
  }
  k_pre1<<<1024, 256, 0, stream>>>(ABUF, RQ1D, bq1, PRE1);
  // fp8 repacks overlay the (now-dead) RQ1D region — must follow k_pre1
  k_repack8<<<32 * 16, 64, 0, stream>>>(Wq2, RQ28, 512, 0, 16);
  k_repack8<<<32 * 16, 64, 0, stream>>>(Wq3, RQ38, 512, 0, 16);
  k_repack8<<<16 * 16, 64, 0, stream>>>(Wqg, RQG8, 512, 0, 16);
  k_repack8<<<32 * 4, 64, 0, stream>>>(Wq1, RQ1Z8, 1152, 1024, 4);
  // 158464 B dyn LDS: zs(2176) + hA(8320) + hB/gs(16896) + w2s(131072)
  k_qscan<<<4, 1024, 158464, stream>>>(PRE1, RQ1Z8, RQ28, RQ38, RQG8,
                                       bq2, bq3, bqg, eps, ZBF, QMU, QSD);
  k_pnet<<<1024, 256, 0, stream>>>(DBUF, ZBF, RP1, RP2, RP3, RPG, RD,
                                   bp1, bp2, bp3, bpg, bd, QMU, QSD, x, xsl,
                                   LP, KL);
  k_final<<<1, 64, 0, stream>>>(LP, KL, (float*)d_out);
}